// Round 1
// baseline (368.573 us; speedup 1.0000x reference)
//
#include <hip/hip_runtime.h>
#include <hip/hip_bf16.h>
#include <math.h>

#define NB   1024
#define LL   100
#define DD   256
#define DINN 704
#define VV   32000
#define RR   129
#define KAV  512

typedef float f32x4 __attribute__((ext_vector_type(4)));
typedef short s16x8 __attribute__((ext_vector_type(8)));

__device__ __forceinline__ float sigf(float x) { return 1.0f / (1.0f + __expf(-x)); }

__device__ __forceinline__ unsigned short f2bf(float f) {
    unsigned int u = __float_as_uint(f);
    u += 0x7fffu + ((u >> 16) & 1u);
    return (unsigned short)(u >> 16);
}
__device__ __forceinline__ float bf2f(unsigned short s) {
    return __uint_as_float(((unsigned int)s) << 16);
}

// ---------------------------------------------------------------------------
// K1: LSTM cell. gates = x@W_ih^T + h0@W_hh^T + b_ih + b_hh  -> h, c
// Tile: 64 rows x 64 gate-cols, where the 64 cols = 16 d-values x 4 gates
// (n = g*256 + dg*16 + i) so the pointwise i/f/g/o combine is block-local.
// ---------------------------------------------------------------------------
__global__ __launch_bounds__(256) void k_lstm(
    const float* __restrict__ x, const float* __restrict__ h0, const float* __restrict__ c0,
    const float* __restrict__ W_ih, const float* __restrict__ b_ih,
    const float* __restrict__ W_hh, const float* __restrict__ b_hh,
    float* __restrict__ out_h, float* __restrict__ out_c)
{
    __shared__ __align__(16) float As[16][68];
    __shared__ __align__(16) float Bs[16][68];
    __shared__ __align__(16) float gsm[64][68];
    const int t = threadIdx.x;
    const int row0 = blockIdx.x * 64;
    const int dg = blockIdx.y;            // 0..15 : which 16-wide d group
    const int tr = t >> 4, tc = t & 15;
    float acc[4][4] = {};

    for (int kt = 0; kt < 60; ++kt) {
        const float* __restrict__ Asrc;
        const float* __restrict__ Bsrc;
        int lda, kb;
        if (kt < 44) { Asrc = x;  Bsrc = W_ih; lda = DINN; kb = kt * 16; }
        else         { Asrc = h0; Bsrc = W_hh; lda = DD;   kb = (kt - 44) * 16; }
        __syncthreads();
#pragma unroll
        for (int p = 0; p < 4; ++p) {
            int e = t + p * 256;
            int r = e >> 4, kk = e & 15;
            As[kk][r] = Asrc[(row0 + r) * lda + kb + kk];
            int n = ((r >> 4) << 8) + dg * 16 + (r & 15);   // (c/16)*256 + dg*16 + c%16
            Bs[kk][r] = Bsrc[n * lda + kb + kk];
        }
        __syncthreads();
#pragma unroll
        for (int kk = 0; kk < 16; ++kk) {
            f32x4 a = *reinterpret_cast<const f32x4*>(&As[kk][tr * 4]);
            f32x4 b = *reinterpret_cast<const f32x4*>(&Bs[kk][tc * 4]);
#pragma unroll
            for (int j = 0; j < 4; ++j)
#pragma unroll
                for (int i = 0; i < 4; ++i)
                    acc[j][i] = fmaf(a[j], b[i], acc[j][i]);
        }
    }
    __syncthreads();
#pragma unroll
    for (int j = 0; j < 4; ++j)
#pragma unroll
        for (int i = 0; i < 4; ++i)
            gsm[tr * 4 + j][tc * 4 + i] = acc[j][i];
    __syncthreads();

#pragma unroll
    for (int p = 0; p < 4; ++p) {
        int item = t + p * 256;          // 64 rows x 16 d
        int r = item >> 4, di = item & 15;
        int dcol = dg * 16 + di;
        float iv = gsm[r][di]      + b_ih[dcol]          + b_hh[dcol];
        float fv = gsm[r][16 + di] + b_ih[DD + dcol]     + b_hh[DD + dcol];
        float gv = gsm[r][32 + di] + b_ih[2 * DD + dcol] + b_hh[2 * DD + dcol];
        float ov = gsm[r][48 + di] + b_ih[3 * DD + dcol] + b_hh[3 * DD + dcol];
        float cprev = c0[(row0 + r) * DD + dcol];
        float cc = sigf(fv) * cprev + sigf(iv) * tanhf(gv);
        float hh = sigf(ov) * tanhf(cc);
        out_c[(row0 + r) * DD + dcol] = cc;
        out_h[(row0 + r) * DD + dcol] = hh;
    }
}

// ---------------------------------------------------------------------------
// K2: hW = h @ W_attn   (W_attn indexed [d][e], non-transposed product)
// ---------------------------------------------------------------------------
__global__ __launch_bounds__(256) void k_hw(
    const float* __restrict__ h, const float* __restrict__ W_attn, float* __restrict__ hW)
{
    __shared__ __align__(16) float As[16][68];
    __shared__ __align__(16) float Bs[16][68];
    const int t = threadIdx.x;
    const int row0 = blockIdx.x * 64;
    const int col0 = blockIdx.y * 64;
    const int tr = t >> 4, tc = t & 15;
    float acc[4][4] = {};
    for (int kt = 0; kt < 16; ++kt) {
        __syncthreads();
#pragma unroll
        for (int p = 0; p < 4; ++p) {
            int e = t + p * 256;
            { int r = e >> 4, kk = e & 15;
              As[kk][r] = h[(row0 + r) * DD + kt * 16 + kk]; }
            { int kk = e >> 6, c = e & 63;
              Bs[kk][c] = W_attn[(kt * 16 + kk) * DD + col0 + c]; }
        }
        __syncthreads();
#pragma unroll
        for (int kk = 0; kk < 16; ++kk) {
            f32x4 a = *reinterpret_cast<const f32x4*>(&As[kk][tr * 4]);
            f32x4 b = *reinterpret_cast<const f32x4*>(&Bs[kk][tc * 4]);
#pragma unroll
            for (int j = 0; j < 4; ++j)
#pragma unroll
                for (int i = 0; i < 4; ++i)
                    acc[j][i] = fmaf(a[j], b[i], acc[j][i]);
        }
    }
#pragma unroll
    for (int j = 0; j < 4; ++j) {
        f32x4 v;
#pragma unroll
        for (int i = 0; i < 4; ++i) v[i] = acc[j][i];
        *reinterpret_cast<f32x4*>(&hW[(row0 + tr * 4 + j) * DD + col0 + tc * 4]) = v;
    }
}

// ---------------------------------------------------------------------------
// K3: per-row attention. scores fp32 from global, enc staged bf16 for ctx.
// ---------------------------------------------------------------------------
__global__ __launch_bounds__(256) void k_attn(
    const float* __restrict__ src_enc, const float* __restrict__ hW, float* __restrict__ ctx_out)
{
    __shared__ __align__(16) unsigned short enc_s[LL * DD];
    __shared__ float sc_s[LL];
    __shared__ float al_s[LL];
    const int b = blockIdx.x, t = threadIdx.x;
    const int lane = t & 63, w = t >> 6;
    const float* __restrict__ enc = src_enc + (size_t)b * LL * DD;
    f32x4 hw4 = *reinterpret_cast<const f32x4*>(&hW[b * DD + lane * 4]);

    for (int l = w; l < LL; l += 4) {
        f32x4 ev = *reinterpret_cast<const f32x4*>(&enc[l * DD + lane * 4]);
        float pr = hw4[0] * ev[0] + hw4[1] * ev[1] + hw4[2] * ev[2] + hw4[3] * ev[3];
#pragma unroll
        for (int m = 1; m < 64; m <<= 1) pr += __shfl_xor(pr, m);
        if (lane == 0) sc_s[l] = pr;
        unsigned short* es = &enc_s[l * DD + lane * 4];
        es[0] = f2bf(ev[0]); es[1] = f2bf(ev[1]); es[2] = f2bf(ev[2]); es[3] = f2bf(ev[3]);
    }
    __syncthreads();
    if (w == 0) {
        float v0 = sc_s[lane];
        float v1 = (lane + 64 < LL) ? sc_s[lane + 64] : -1e30f;
        float m = fmaxf(v0, v1);
#pragma unroll
        for (int s = 1; s < 64; s <<= 1) m = fmaxf(m, __shfl_xor(m, s));
        float e0 = __expf(v0 - m);
        float e1 = (lane + 64 < LL) ? __expf(v1 - m) : 0.f;
        float ssum = e0 + e1;
#pragma unroll
        for (int s = 1; s < 64; s <<= 1) ssum += __shfl_xor(ssum, s);
        float inv = 1.f / ssum;
        al_s[lane] = e0 * inv;
        if (lane + 64 < LL) al_s[lane + 64] = e1 * inv;
    }
    __syncthreads();
    float accv = 0.f;
    for (int l = 0; l < LL; ++l) accv += al_s[l] * bf2f(enc_s[l * DD + t]);
    ctx_out[b * DD + t] = accv;
}

// ---------------------------------------------------------------------------
// K4: att = tanh(concat(h, ctx) @ W_att_vec^T)
// ---------------------------------------------------------------------------
__global__ __launch_bounds__(256) void k_attvec(
    const float* __restrict__ h, const float* __restrict__ ctx,
    const float* __restrict__ W_att_vec, float* __restrict__ att_out)
{
    __shared__ __align__(16) float As[16][68];
    __shared__ __align__(16) float Bs[16][68];
    const int t = threadIdx.x;
    const int row0 = blockIdx.x * 64;
    const int col0 = blockIdx.y * 64;
    const int tr = t >> 4, tc = t & 15;
    float acc[4][4] = {};
    for (int kt = 0; kt < 32; ++kt) {
        const float* __restrict__ Asrc = (kt < 16) ? h : ctx;
        int kb = (kt < 16) ? kt * 16 : (kt - 16) * 16;
        int kg = kt * 16;
        __syncthreads();
#pragma unroll
        for (int p = 0; p < 4; ++p) {
            int e = t + p * 256;
            int r = e >> 4, kk = e & 15;
            As[kk][r] = Asrc[(row0 + r) * DD + kb + kk];
            Bs[kk][r] = W_att_vec[(col0 + r) * KAV + kg + kk];
        }
        __syncthreads();
#pragma unroll
        for (int kk = 0; kk < 16; ++kk) {
            f32x4 a = *reinterpret_cast<const f32x4*>(&As[kk][tr * 4]);
            f32x4 b = *reinterpret_cast<const f32x4*>(&Bs[kk][tc * 4]);
#pragma unroll
            for (int j = 0; j < 4; ++j)
#pragma unroll
                for (int i = 0; i < 4; ++i)
                    acc[j][i] = fmaf(a[j], b[i], acc[j][i]);
        }
    }
#pragma unroll
    for (int j = 0; j < 4; ++j)
#pragma unroll
        for (int i = 0; i < 4; ++i)
            att_out[(row0 + tr * 4 + j) * DD + col0 + tc * 4 + i] = tanhf(acc[j][i]);
}

// ---------------------------------------------------------------------------
// K5: rule_proj[r][d] = rule_emb[r] . W_rule_proj[d]
// ---------------------------------------------------------------------------
__global__ __launch_bounds__(256) void k_ruleproj(
    const float* __restrict__ rule_emb, const float* __restrict__ W_rule_proj,
    float* __restrict__ rule_proj)
{
    __shared__ float re_s[128];
    const int r = blockIdx.x, d = threadIdx.x;
    if (d < 128) re_s[d] = rule_emb[r * 128 + d];
    __syncthreads();
    float acc = 0.f;
    const float* __restrict__ wr = &W_rule_proj[d * 128];
#pragma unroll 8
    for (int k = 0; k < 128; k += 4) {
        f32x4 w4 = *reinterpret_cast<const f32x4*>(&wr[k]);
        acc += w4[0] * re_s[k] + w4[1] * re_s[k + 1] + w4[2] * re_s[k + 2] + w4[3] * re_s[k + 3];
    }
    rule_proj[r * DD + d] = acc;
}

// ---------------------------------------------------------------------------
// K6: per-row readouts: rule log-softmax, atW=att@W_ptr, att_p=att@W_prim_proj,
//     gate, ptr scores + copy_mass. All fp32.
// ---------------------------------------------------------------------------
__global__ __launch_bounds__(256) void k_readout(
    const float* __restrict__ att, const float* __restrict__ src_enc,
    const float* __restrict__ rule_proj, const float* __restrict__ W_ptr,
    const float* __restrict__ W_prim_proj, const float* __restrict__ w_gen,
    const float* __restrict__ b_gen,
    float* __restrict__ log_p_rule, float* __restrict__ att_p,
    float* __restrict__ gate0_ws, float* __restrict__ copy_mass)
{
    __shared__ __align__(16) float att_s[DD];
    __shared__ __align__(16) float atw_s[DD];
    __shared__ float red_s[RR];
    __shared__ float sc_s[LL];
    __shared__ float gl_s[2];
    __shared__ float mS[2];
    const int b = blockIdx.x, t = threadIdx.x;
    const int lane = t & 63, w = t >> 6;
    att_s[t] = att[b * DD + t];
    __syncthreads();

    if (t < RR) {
        float acc = 0.f;
        const float* __restrict__ rp = &rule_proj[t * DD];
        for (int d = 0; d < DD; d += 4) {
            f32x4 r4 = *reinterpret_cast<const f32x4*>(&rp[d]);
            f32x4 a4 = *reinterpret_cast<const f32x4*>(&att_s[d]);
            acc += r4[0] * a4[0] + r4[1] * a4[1] + r4[2] * a4[2] + r4[3] * a4[3];
        }
        red_s[t] = acc;
    }
    {
        float aw = 0.f;
        for (int d = 0; d < DD; ++d) aw += att_s[d] * W_ptr[d * DD + t];
        atw_s[t] = aw;
    }
    if (t < 128) {
        float ap = 0.f;
        for (int d = 0; d < DD; ++d) ap += att_s[d] * W_prim_proj[d * 128 + t];
        att_p[b * 128 + t] = ap;
    }
    if (w < 2) {
        f32x4 a4 = *reinterpret_cast<const f32x4*>(&att_s[lane * 4]);
        f32x4 g4 = *reinterpret_cast<const f32x4*>(&w_gen[w * DD + lane * 4]);
        float p = a4[0] * g4[0] + a4[1] * g4[1] + a4[2] * g4[2] + a4[3] * g4[3];
#pragma unroll
        for (int s = 1; s < 64; s <<= 1) p += __shfl_xor(p, s);
        if (lane == 0) gl_s[w] = p + b_gen[w];
    }
    __syncthreads();

    if (w == 0) {  // log-softmax stats over 129
        float v0 = red_s[lane];
        float v1 = red_s[lane + 64];
        float v2 = (lane == 0) ? red_s[128] : -1e30f;
        float m = fmaxf(fmaxf(v0, v1), v2);
#pragma unroll
        for (int s = 1; s < 64; s <<= 1) m = fmaxf(m, __shfl_xor(m, s));
        float ssum = __expf(v0 - m) + __expf(v1 - m) + ((lane == 0) ? __expf(v2 - m) : 0.f);
#pragma unroll
        for (int s = 1; s < 64; s <<= 1) ssum += __shfl_xor(ssum, s);
        if (lane == 0) { mS[0] = m; mS[1] = logf(ssum); }
    }
    __syncthreads();
    if (t < RR) log_p_rule[b * RR + t] = red_s[t] - mS[0] - mS[1];

    float g0 = gl_s[0], g1 = gl_s[1];
    float gm = fmaxf(g0, g1);
    float e0 = __expf(g0 - gm), e1 = __expf(g1 - gm);
    float gate1 = e1 / (e0 + e1);
    if (t == 0) gate0_ws[b] = e0 / (e0 + e1);

    // pointer scores, fp32 straight from global (coalesced)
    const float* __restrict__ enc = src_enc + (size_t)b * LL * DD;
    f32x4 aw4 = *reinterpret_cast<const f32x4*>(&atw_s[lane * 4]);
    for (int l = w; l < LL; l += 4) {
        f32x4 ev = *reinterpret_cast<const f32x4*>(&enc[l * DD + lane * 4]);
        float pr = aw4[0] * ev[0] + aw4[1] * ev[1] + aw4[2] * ev[2] + aw4[3] * ev[3];
#pragma unroll
        for (int m = 1; m < 64; m <<= 1) pr += __shfl_xor(pr, m);
        if (lane == 0) sc_s[l] = pr;
    }
    __syncthreads();
    if (w == 0) {
        float v0 = sc_s[lane];
        float v1 = (lane + 64 < LL) ? sc_s[lane + 64] : -1e30f;
        float m = fmaxf(v0, v1);
#pragma unroll
        for (int s = 1; s < 64; s <<= 1) m = fmaxf(m, __shfl_xor(m, s));
        float ee0 = __expf(v0 - m);
        float ee1 = (lane + 64 < LL) ? __expf(v1 - m) : 0.f;
        float ssum = ee0 + ee1;
#pragma unroll
        for (int s = 1; s < 64; s <<= 1) ssum += __shfl_xor(ssum, s);
        float inv = 1.f / ssum;
        copy_mass[b * LL + lane] = gate1 * ee0 * inv;
        if (lane + 64 < LL) copy_mass[b * LL + lane + 64] = gate1 * ee1 * inv;
    }
}

// ---------------------------------------------------------------------------
// K7: logits = att_p @ prim_emb^T  via bf16 MFMA (K=128).
// PASS 0: per-(row, 64-col-chunk) max & sumexp partials.
// PASS 1: recompute, write p_prim = coef[row]*exp(v - rowM[row]).
// ---------------------------------------------------------------------------
__device__ __forceinline__ s16x8 pack_bf8(const float* __restrict__ p) {
    f32x4 a = *reinterpret_cast<const f32x4*>(p);
    f32x4 b = *reinterpret_cast<const f32x4*>(p + 4);
    s16x8 r;
    r[0] = (short)f2bf(a[0]); r[1] = (short)f2bf(a[1]);
    r[2] = (short)f2bf(a[2]); r[3] = (short)f2bf(a[3]);
    r[4] = (short)f2bf(b[0]); r[5] = (short)f2bf(b[1]);
    r[6] = (short)f2bf(b[2]); r[7] = (short)f2bf(b[3]);
    return r;
}

template <int PASS>
__global__ __launch_bounds__(256) void k_prim(
    const float* __restrict__ att_p, const float* __restrict__ prim_emb,
    const float* __restrict__ rowM, const float* __restrict__ coef,
    float* __restrict__ stats, float* __restrict__ p_prim)
{
    const int t = threadIdx.x;
    const int lane = t & 63, w = t >> 6;
    const int rowbase = blockIdx.y * 128 + (w >> 1) * 64;
    const int colbase = blockIdx.x * 128 + (w & 1) * 64;
    const int lm = lane & 15, lq = lane >> 4;
    f32x4 acc[4][4] = {};

#pragma unroll
    for (int kg = 0; kg < 4; ++kg) {
        const int ko = kg * 32 + lq * 8;
        s16x8 afr[4], bfr[4];
#pragma unroll
        for (int rg = 0; rg < 4; ++rg)
            afr[rg] = pack_bf8(&att_p[(rowbase + rg * 16 + lm) * 128 + ko]);
#pragma unroll
        for (int cg = 0; cg < 4; ++cg)
            bfr[cg] = pack_bf8(&prim_emb[(size_t)(colbase + cg * 16 + lm) * 128 + ko]);
#pragma unroll
        for (int rg = 0; rg < 4; ++rg)
#pragma unroll
            for (int cg = 0; cg < 4; ++cg)
                acc[rg][cg] = __builtin_amdgcn_mfma_f32_16x16x32_bf16(
                    afr[rg], bfr[cg], acc[rg][cg], 0, 0, 0);
    }

    if (PASS == 0) {
#pragma unroll
        for (int rg = 0; rg < 4; ++rg) {
#pragma unroll
            for (int r = 0; r < 4; ++r) {
                float v0 = acc[rg][0][r], v1 = acc[rg][1][r];
                float v2 = acc[rg][2][r], v3 = acc[rg][3][r];
                float m = fmaxf(fmaxf(v0, v1), fmaxf(v2, v3));
#pragma unroll
                for (int s = 1; s < 16; s <<= 1) m = fmaxf(m, __shfl_xor(m, s));
                float se = __expf(v0 - m) + __expf(v1 - m) + __expf(v2 - m) + __expf(v3 - m);
#pragma unroll
                for (int s = 1; s < 16; s <<= 1) se += __shfl_xor(se, s);
                if (lm == 0) {
                    int row = rowbase + rg * 16 + lq * 4 + r;
                    int chunk = colbase >> 6;
                    stats[(row * 500 + chunk) * 2 + 0] = m;
                    stats[(row * 500 + chunk) * 2 + 1] = se;
                }
            }
        }
    } else {
#pragma unroll
        for (int rg = 0; rg < 4; ++rg) {
            int row = rowbase + rg * 16 + lq * 4;
#pragma unroll
            for (int r = 0; r < 4; ++r) {
                float rm = rowM[row + r];
                float cf = coef[row + r];
#pragma unroll
                for (int cg = 0; cg < 4; ++cg) {
                    p_prim[(size_t)(row + r) * VV + colbase + cg * 16 + lm] =
                        cf * __expf(acc[rg][cg][r] - rm);
                }
            }
        }
    }
}

// ---------------------------------------------------------------------------
// K8: combine per-chunk stats -> rowM, coef = gate0 / sumexp (deterministic)
// ---------------------------------------------------------------------------
__global__ __launch_bounds__(256) void k_combine(
    const float* __restrict__ stats, const float* __restrict__ gate0_ws,
    float* __restrict__ rowM, float* __restrict__ coef)
{
    const int w = threadIdx.x >> 6, lane = threadIdx.x & 63;
    const int row = blockIdx.x * 4 + w;
    float m = -1e30f;
    for (int c = lane; c < 500; c += 64) m = fmaxf(m, stats[(row * 500 + c) * 2]);
#pragma unroll
    for (int s = 1; s < 64; s <<= 1) m = fmaxf(m, __shfl_xor(m, s));
    float se = 0.f;
    for (int c = lane; c < 500; c += 64)
        se += stats[(row * 500 + c) * 2 + 1] * __expf(stats[(row * 500 + c) * 2] - m);
#pragma unroll
    for (int s = 1; s < 64; s <<= 1) se += __shfl_xor(se, s);
    if (lane == 0) { rowM[row] = m; coef[row] = gate0_ws[row] / se; }
}

// ---------------------------------------------------------------------------
// K9: scatter copy mass into p_prim rows
// ---------------------------------------------------------------------------
__global__ __launch_bounds__(256) void k_scatter(
    const int* __restrict__ tok, const float* __restrict__ copy_mass, float* __restrict__ p_prim)
{
    int i = blockIdx.x * 256 + threadIdx.x;
    if (i >= NB * LL) return;
    int b = i / LL;
    atomicAdd(&p_prim[(size_t)b * VV + tok[i]], copy_mass[i]);
}

// ---------------------------------------------------------------------------
extern "C" void kernel_launch(void* const* d_in, const int* in_sizes, int n_in,
                              void* d_out, int out_size, void* d_ws, size_t ws_size,
                              hipStream_t stream)
{
    const float* x         = (const float*)d_in[0];
    const float* h0        = (const float*)d_in[1];
    const float* c0        = (const float*)d_in[2];
    const float* src_enc   = (const float*)d_in[3];
    const int*   tok       = (const int*)  d_in[4];
    const float* W_ih      = (const float*)d_in[5];
    const float* b_ih      = (const float*)d_in[6];
    const float* W_hh      = (const float*)d_in[7];
    const float* b_hh      = (const float*)d_in[8];
    const float* W_attn    = (const float*)d_in[9];
    const float* W_att_vec = (const float*)d_in[10];
    const float* W_ptr     = (const float*)d_in[11];
    const float* rule_emb  = (const float*)d_in[12];
    const float* W_rule_pr = (const float*)d_in[13];
    const float* prim_emb  = (const float*)d_in[14];
    const float* W_prim_pr = (const float*)d_in[15];
    const float* w_gen     = (const float*)d_in[16];
    const float* b_gen     = (const float*)d_in[17];

    float* out    = (float*)d_out;
    float* o_logp = out;                               // [1024,129]
    float* o_pp   = out + 1024 * 129;                  // [1024,32000]
    float* o_h    = o_pp + (size_t)1024 * 32000;       // [1024,256]
    float* o_c    = o_h + 1024 * 256;                  // [1024,256]
    float* o_att  = o_c + 1024 * 256;                  // [1024,256]

    float* wsf      = (float*)d_ws;
    float* ws_ctx   = wsf;                   // 262144
    float* ws_hW    = ws_ctx  + 262144;      // 262144
    float* ws_rp    = ws_hW   + 262144;      // 33280 (129*256 padded)
    float* ws_attp  = ws_rp   + 33280;       // 131072
    float* ws_gate  = ws_attp + 131072;      // 1024
    float* ws_cm    = ws_gate + 1024;        // 102400
    float* ws_rowM  = ws_cm   + 102400;      // 1024
    float* ws_coef  = ws_rowM + 1024;        // 1024
    float* ws_stats = ws_coef + 1024;        // 1024000  (total ~7.3 MB)

    k_lstm<<<dim3(16, 16), 256, 0, stream>>>(x, h0, c0, W_ih, b_ih, W_hh, b_hh, o_h, o_c);
    k_hw<<<dim3(16, 4), 256, 0, stream>>>(o_h, W_attn, ws_hW);
    k_attn<<<dim3(1024), 256, 0, stream>>>(src_enc, ws_hW, ws_ctx);
    k_attvec<<<dim3(16, 4), 256, 0, stream>>>(o_h, ws_ctx, W_att_vec, o_att);
    k_ruleproj<<<dim3(129), 256, 0, stream>>>(rule_emb, W_rule_pr, ws_rp);
    k_readout<<<dim3(1024), 256, 0, stream>>>(o_att, src_enc, ws_rp, W_ptr, W_prim_pr,
                                              w_gen, b_gen, o_logp, ws_attp, ws_gate, ws_cm);
    k_prim<0><<<dim3(250, 8), 256, 0, stream>>>(ws_attp, prim_emb, nullptr, nullptr, ws_stats, nullptr);
    k_combine<<<dim3(256), 256, 0, stream>>>(ws_stats, ws_gate, ws_rowM, ws_coef);
    k_prim<1><<<dim3(250, 8), 256, 0, stream>>>(ws_attp, prim_emb, ws_rowM, ws_coef, nullptr, o_pp);
    k_scatter<<<dim3(400), 256, 0, stream>>>(tok, ws_cm, o_pp);
}

// Round 3
// 295.088 us; speedup vs baseline: 1.2490x; 1.2490x over previous
//
#include <hip/hip_runtime.h>
#include <hip/hip_bf16.h>
#include <math.h>

#define NB   1024
#define LL   100
#define DD   256
#define DINN 704
#define VV   32000
#define RR   129
#define KAV  512

typedef float f32x4 __attribute__((ext_vector_type(4)));
typedef short s16x8 __attribute__((ext_vector_type(8)));
typedef unsigned short u16;

__device__ __forceinline__ float sigf(float x) { return 1.0f / (1.0f + __expf(-x)); }

__device__ __forceinline__ u16 f2bf(float f) {
    unsigned int u = __float_as_uint(f);
    u += 0x7fffu + ((u >> 16) & 1u);
    return (u16)(u >> 16);
}
__device__ __forceinline__ float bf2f(u16 s) {
    return __uint_as_float(((unsigned int)s) << 16);
}

// ---------------------------------------------------------------------------
// K1: LSTM cell. gates = x@W_ih^T + h0@W_hh^T + b_ih + b_hh  -> h, c
// ---------------------------------------------------------------------------
__global__ __launch_bounds__(256) void k_lstm(
    const float* __restrict__ x, const float* __restrict__ h0, const float* __restrict__ c0,
    const float* __restrict__ W_ih, const float* __restrict__ b_ih,
    const float* __restrict__ W_hh, const float* __restrict__ b_hh,
    float* __restrict__ out_h, float* __restrict__ out_c)
{
    __shared__ __align__(16) float As[16][68];
    __shared__ __align__(16) float Bs[16][68];
    __shared__ __align__(16) float gsm[64][68];
    const int t = threadIdx.x;
    const int row0 = blockIdx.x * 64;
    const int dg = blockIdx.y;            // 0..15 : which 16-wide d group
    const int tr = t >> 4, tc = t & 15;
    float acc[4][4] = {};

    for (int kt = 0; kt < 60; ++kt) {
        const float* __restrict__ Asrc;
        const float* __restrict__ Bsrc;
        int lda, kb;
        if (kt < 44) { Asrc = x;  Bsrc = W_ih; lda = DINN; kb = kt * 16; }
        else         { Asrc = h0; Bsrc = W_hh; lda = DD;   kb = (kt - 44) * 16; }
        __syncthreads();
#pragma unroll
        for (int p = 0; p < 4; ++p) {
            int e = t + p * 256;
            int r = e >> 4, kk = e & 15;
            As[kk][r] = Asrc[(row0 + r) * lda + kb + kk];
            int n = ((r >> 4) << 8) + dg * 16 + (r & 15);
            Bs[kk][r] = Bsrc[n * lda + kb + kk];
        }
        __syncthreads();
#pragma unroll
        for (int kk = 0; kk < 16; ++kk) {
            f32x4 a = *reinterpret_cast<const f32x4*>(&As[kk][tr * 4]);
            f32x4 b = *reinterpret_cast<const f32x4*>(&Bs[kk][tc * 4]);
#pragma unroll
            for (int j = 0; j < 4; ++j)
#pragma unroll
                for (int i = 0; i < 4; ++i)
                    acc[j][i] = fmaf(a[j], b[i], acc[j][i]);
        }
    }
    __syncthreads();
#pragma unroll
    for (int j = 0; j < 4; ++j)
#pragma unroll
        for (int i = 0; i < 4; ++i)
            gsm[tr * 4 + j][tc * 4 + i] = acc[j][i];
    __syncthreads();

#pragma unroll
    for (int p = 0; p < 4; ++p) {
        int item = t + p * 256;
        int r = item >> 4, di = item & 15;
        int dcol = dg * 16 + di;
        float iv = gsm[r][di]      + b_ih[dcol]          + b_hh[dcol];
        float fv = gsm[r][16 + di] + b_ih[DD + dcol]     + b_hh[DD + dcol];
        float gv = gsm[r][32 + di] + b_ih[2 * DD + dcol] + b_hh[2 * DD + dcol];
        float ov = gsm[r][48 + di] + b_ih[3 * DD + dcol] + b_hh[3 * DD + dcol];
        float cprev = c0[(row0 + r) * DD + dcol];
        float cc = sigf(fv) * cprev + sigf(iv) * tanhf(gv);
        float hh = sigf(ov) * tanhf(cc);
        out_c[(row0 + r) * DD + dcol] = cc;
        out_h[(row0 + r) * DD + dcol] = hh;
    }
}

// ---------------------------------------------------------------------------
// K2: hW = h @ W_attn
// ---------------------------------------------------------------------------
__global__ __launch_bounds__(256) void k_hw(
    const float* __restrict__ h, const float* __restrict__ W_attn, float* __restrict__ hW)
{
    __shared__ __align__(16) float As[16][68];
    __shared__ __align__(16) float Bs[16][68];
    const int t = threadIdx.x;
    const int row0 = blockIdx.x * 64;
    const int col0 = blockIdx.y * 64;
    const int tr = t >> 4, tc = t & 15;
    float acc[4][4] = {};
    for (int kt = 0; kt < 16; ++kt) {
        __syncthreads();
#pragma unroll
        for (int p = 0; p < 4; ++p) {
            int e = t + p * 256;
            { int r = e >> 4, kk = e & 15;
              As[kk][r] = h[(row0 + r) * DD + kt * 16 + kk]; }
            { int kk = e >> 6, c = e & 63;
              Bs[kk][c] = W_attn[(kt * 16 + kk) * DD + col0 + c]; }
        }
        __syncthreads();
#pragma unroll
        for (int kk = 0; kk < 16; ++kk) {
            f32x4 a = *reinterpret_cast<const f32x4*>(&As[kk][tr * 4]);
            f32x4 b = *reinterpret_cast<const f32x4*>(&Bs[kk][tc * 4]);
#pragma unroll
            for (int j = 0; j < 4; ++j)
#pragma unroll
                for (int i = 0; i < 4; ++i)
                    acc[j][i] = fmaf(a[j], b[i], acc[j][i]);
        }
    }
#pragma unroll
    for (int j = 0; j < 4; ++j) {
        f32x4 v;
#pragma unroll
        for (int i = 0; i < 4; ++i) v[i] = acc[j][i];
        *reinterpret_cast<f32x4*>(&hW[(row0 + tr * 4 + j) * DD + col0 + tc * 4]) = v;
    }
}

// ---------------------------------------------------------------------------
// K3: per-row attention
// ---------------------------------------------------------------------------
__global__ __launch_bounds__(256) void k_attn(
    const float* __restrict__ src_enc, const float* __restrict__ hW, float* __restrict__ ctx_out)
{
    __shared__ __align__(16) u16 enc_s[LL * DD];
    __shared__ float sc_s[LL];
    __shared__ float al_s[LL];
    const int b = blockIdx.x, t = threadIdx.x;
    const int lane = t & 63, w = t >> 6;
    const float* __restrict__ enc = src_enc + (size_t)b * LL * DD;
    f32x4 hw4 = *reinterpret_cast<const f32x4*>(&hW[b * DD + lane * 4]);

    for (int l = w; l < LL; l += 4) {
        f32x4 ev = *reinterpret_cast<const f32x4*>(&enc[l * DD + lane * 4]);
        float pr = hw4[0] * ev[0] + hw4[1] * ev[1] + hw4[2] * ev[2] + hw4[3] * ev[3];
#pragma unroll
        for (int m = 1; m < 64; m <<= 1) pr += __shfl_xor(pr, m);
        if (lane == 0) sc_s[l] = pr;
        u16* es = &enc_s[l * DD + lane * 4];
        es[0] = f2bf(ev[0]); es[1] = f2bf(ev[1]); es[2] = f2bf(ev[2]); es[3] = f2bf(ev[3]);
    }
    __syncthreads();
    if (w == 0) {
        float v0 = sc_s[lane];
        float v1 = (lane + 64 < LL) ? sc_s[lane + 64] : -1e30f;
        float m = fmaxf(v0, v1);
#pragma unroll
        for (int s = 1; s < 64; s <<= 1) m = fmaxf(m, __shfl_xor(m, s));
        float e0 = __expf(v0 - m);
        float e1 = (lane + 64 < LL) ? __expf(v1 - m) : 0.f;
        float ssum = e0 + e1;
#pragma unroll
        for (int s = 1; s < 64; s <<= 1) ssum += __shfl_xor(ssum, s);
        float inv = 1.f / ssum;
        al_s[lane] = e0 * inv;
        if (lane + 64 < LL) al_s[lane + 64] = e1 * inv;
    }
    __syncthreads();
    float accv = 0.f;
    for (int l = 0; l < LL; ++l) accv += al_s[l] * bf2f(enc_s[l * DD + t]);
    ctx_out[b * DD + t] = accv;
}

// ---------------------------------------------------------------------------
// K4: att = tanh(concat(h, ctx) @ W_att_vec^T)
// ---------------------------------------------------------------------------
__global__ __launch_bounds__(256) void k_attvec(
    const float* __restrict__ h, const float* __restrict__ ctx,
    const float* __restrict__ W_att_vec, float* __restrict__ att_out)
{
    __shared__ __align__(16) float As[16][68];
    __shared__ __align__(16) float Bs[16][68];
    const int t = threadIdx.x;
    const int row0 = blockIdx.x * 64;
    const int col0 = blockIdx.y * 64;
    const int tr = t >> 4, tc = t & 15;
    float acc[4][4] = {};
    for (int kt = 0; kt < 32; ++kt) {
        const float* __restrict__ Asrc = (kt < 16) ? h : ctx;
        int kb = (kt < 16) ? kt * 16 : (kt - 16) * 16;
        int kg = kt * 16;
        __syncthreads();
#pragma unroll
        for (int p = 0; p < 4; ++p) {
            int e = t + p * 256;
            int r = e >> 4, kk = e & 15;
            As[kk][r] = Asrc[(row0 + r) * DD + kb + kk];
            Bs[kk][r] = W_att_vec[(col0 + r) * KAV + kg + kk];
        }
        __syncthreads();
#pragma unroll
        for (int kk = 0; kk < 16; ++kk) {
            f32x4 a = *reinterpret_cast<const f32x4*>(&As[kk][tr * 4]);
            f32x4 b = *reinterpret_cast<const f32x4*>(&Bs[kk][tc * 4]);
#pragma unroll
            for (int j = 0; j < 4; ++j)
#pragma unroll
                for (int i = 0; i < 4; ++i)
                    acc[j][i] = fmaf(a[j], b[i], acc[j][i]);
        }
    }
#pragma unroll
    for (int j = 0; j < 4; ++j)
#pragma unroll
        for (int i = 0; i < 4; ++i)
            att_out[(row0 + tr * 4 + j) * DD + col0 + tc * 4 + i] = tanhf(acc[j][i]);
}

// ---------------------------------------------------------------------------
// K5: rule_proj[r][d] = rule_emb[r] . W_rule_proj[d]
// ---------------------------------------------------------------------------
__global__ __launch_bounds__(256) void k_ruleproj(
    const float* __restrict__ rule_emb, const float* __restrict__ W_rule_proj,
    float* __restrict__ rule_proj)
{
    __shared__ float re_s[128];
    const int r = blockIdx.x, d = threadIdx.x;
    if (d < 128) re_s[d] = rule_emb[r * 128 + d];
    __syncthreads();
    float acc = 0.f;
    const float* __restrict__ wr = &W_rule_proj[d * 128];
#pragma unroll 8
    for (int k = 0; k < 128; k += 4) {
        f32x4 w4 = *reinterpret_cast<const f32x4*>(&wr[k]);
        acc += w4[0] * re_s[k] + w4[1] * re_s[k + 1] + w4[2] * re_s[k + 2] + w4[3] * re_s[k + 3];
    }
    rule_proj[r * DD + d] = acc;
}

// ---------------------------------------------------------------------------
// K6: per-row readouts. att_p now emitted as bf16.
// ---------------------------------------------------------------------------
__global__ __launch_bounds__(256) void k_readout(
    const float* __restrict__ att, const float* __restrict__ src_enc,
    const float* __restrict__ rule_proj, const float* __restrict__ W_ptr,
    const float* __restrict__ W_prim_proj, const float* __restrict__ w_gen,
    const float* __restrict__ b_gen,
    float* __restrict__ log_p_rule, u16* __restrict__ att_bf,
    float* __restrict__ gate0_ws, float* __restrict__ copy_mass)
{
    __shared__ __align__(16) float att_s[DD];
    __shared__ __align__(16) float atw_s[DD];
    __shared__ float red_s[RR];
    __shared__ float sc_s[LL];
    __shared__ float gl_s[2];
    __shared__ float mS[2];
    const int b = blockIdx.x, t = threadIdx.x;
    const int lane = t & 63, w = t >> 6;
    att_s[t] = att[b * DD + t];
    __syncthreads();

    if (t < RR) {
        float acc = 0.f;
        const float* __restrict__ rp = &rule_proj[t * DD];
        for (int d = 0; d < DD; d += 4) {
            f32x4 r4 = *reinterpret_cast<const f32x4*>(&rp[d]);
            f32x4 a4 = *reinterpret_cast<const f32x4*>(&att_s[d]);
            acc += r4[0] * a4[0] + r4[1] * a4[1] + r4[2] * a4[2] + r4[3] * a4[3];
        }
        red_s[t] = acc;
    }
    {
        float aw = 0.f;
        for (int d = 0; d < DD; ++d) aw += att_s[d] * W_ptr[d * DD + t];
        atw_s[t] = aw;
    }
    if (t < 128) {
        float ap = 0.f;
        for (int d = 0; d < DD; ++d) ap += att_s[d] * W_prim_proj[d * 128 + t];
        att_bf[b * 128 + t] = f2bf(ap);
    }
    if (w < 2) {
        f32x4 a4 = *reinterpret_cast<const f32x4*>(&att_s[lane * 4]);
        f32x4 g4 = *reinterpret_cast<const f32x4*>(&w_gen[w * DD + lane * 4]);
        float p = a4[0] * g4[0] + a4[1] * g4[1] + a4[2] * g4[2] + a4[3] * g4[3];
#pragma unroll
        for (int s = 1; s < 64; s <<= 1) p += __shfl_xor(p, s);
        if (lane == 0) gl_s[w] = p + b_gen[w];
    }
    __syncthreads();

    if (w == 0) {
        float v0 = red_s[lane];
        float v1 = red_s[lane + 64];
        float v2 = (lane == 0) ? red_s[128] : -1e30f;
        float m = fmaxf(fmaxf(v0, v1), v2);
#pragma unroll
        for (int s = 1; s < 64; s <<= 1) m = fmaxf(m, __shfl_xor(m, s));
        float ssum = __expf(v0 - m) + __expf(v1 - m) + ((lane == 0) ? __expf(v2 - m) : 0.f);
#pragma unroll
        for (int s = 1; s < 64; s <<= 1) ssum += __shfl_xor(ssum, s);
        if (lane == 0) { mS[0] = m; mS[1] = logf(ssum); }
    }
    __syncthreads();
    if (t < RR) log_p_rule[b * RR + t] = red_s[t] - mS[0] - mS[1];

    float g0 = gl_s[0], g1 = gl_s[1];
    float gm = fmaxf(g0, g1);
    float e0 = __expf(g0 - gm), e1 = __expf(g1 - gm);
    float gate1 = e1 / (e0 + e1);
    if (t == 0) gate0_ws[b] = e0 / (e0 + e1);

    const float* __restrict__ enc = src_enc + (size_t)b * LL * DD;
    f32x4 aw4 = *reinterpret_cast<const f32x4*>(&atw_s[lane * 4]);
    for (int l = w; l < LL; l += 4) {
        f32x4 ev = *reinterpret_cast<const f32x4*>(&enc[l * DD + lane * 4]);
        float pr = aw4[0] * ev[0] + aw4[1] * ev[1] + aw4[2] * ev[2] + aw4[3] * ev[3];
#pragma unroll
        for (int m = 1; m < 64; m <<= 1) pr += __shfl_xor(pr, m);
        if (lane == 0) sc_s[l] = pr;
    }
    __syncthreads();
    if (w == 0) {
        float v0 = sc_s[lane];
        float v1 = (lane + 64 < LL) ? sc_s[lane + 64] : -1e30f;
        float m = fmaxf(v0, v1);
#pragma unroll
        for (int s = 1; s < 64; s <<= 1) m = fmaxf(m, __shfl_xor(m, s));
        float ee0 = __expf(v0 - m);
        float ee1 = (lane + 64 < LL) ? __expf(v1 - m) : 0.f;
        float ssum = ee0 + ee1;
#pragma unroll
        for (int s = 1; s < 64; s <<= 1) ssum += __shfl_xor(ssum, s);
        float inv = 1.f / ssum;
        copy_mass[b * LL + lane] = gate1 * ee0 * inv;
        if (lane + 64 < LL) copy_mass[b * LL + lane + 64] = gate1 * ee1 * inv;
    }
}

// ---------------------------------------------------------------------------
// K-conv: prim_emb fp32 -> bf16 (32000x128)
// ---------------------------------------------------------------------------
__global__ __launch_bounds__(256) void k_conv(
    const float* __restrict__ src, u16* __restrict__ dst)
{
    int i = (blockIdx.x * 256 + threadIdx.x) * 8;
    f32x4 a = *reinterpret_cast<const f32x4*>(&src[i]);
    f32x4 b = *reinterpret_cast<const f32x4*>(&src[i + 4]);
    s16x8 r;
    r[0] = (short)f2bf(a[0]); r[1] = (short)f2bf(a[1]);
    r[2] = (short)f2bf(a[2]); r[3] = (short)f2bf(a[3]);
    r[4] = (short)f2bf(b[0]); r[5] = (short)f2bf(b[1]);
    r[6] = (short)f2bf(b[2]); r[7] = (short)f2bf(b[3]);
    *reinterpret_cast<s16x8*>(&dst[i]) = r;
}

// ---------------------------------------------------------------------------
// K7: logits = att_bf @ prim_bf^T via bf16 MFMA, K=128, no max (|logit|<=8).
// Block: 128 cols x 256 rows (2 iters of 128). B-frags persistent in regs.
// PASS0: per-(row, 64-col chunk) sumexp partials. PASS1: write p_prim.
// ---------------------------------------------------------------------------
template <int PASS>
__global__ __launch_bounds__(256) void k_prim(
    const u16* __restrict__ att_bf, const u16* __restrict__ prim_bf,
    const float* __restrict__ coef, float* __restrict__ stats, float* __restrict__ p_prim)
{
    const int t = threadIdx.x;
    const int lane = t & 63, w = t >> 6;
    const int lm = lane & 15, lq = lane >> 4;
    const int colbase = blockIdx.x * 128 + (w & 1) * 64;
    const int chunk = colbase >> 6;
    const int rowblk = blockIdx.y * 256;

    s16x8 bfr[4][4];
#pragma unroll
    for (int kg = 0; kg < 4; ++kg)
#pragma unroll
        for (int cg = 0; cg < 4; ++cg)
            bfr[kg][cg] = *reinterpret_cast<const s16x8*>(
                &prim_bf[(size_t)(colbase + cg * 16 + lm) * 128 + kg * 32 + lq * 8]);

    for (int it = 0; it < 2; ++it) {
        const int rowbase = rowblk + it * 128 + (w >> 1) * 64;
        f32x4 acc[4][4] = {};
#pragma unroll
        for (int kg = 0; kg < 4; ++kg) {
            s16x8 afr[4];
#pragma unroll
            for (int rg = 0; rg < 4; ++rg)
                afr[rg] = *reinterpret_cast<const s16x8*>(
                    &att_bf[(rowbase + rg * 16 + lm) * 128 + kg * 32 + lq * 8]);
#pragma unroll
            for (int rg = 0; rg < 4; ++rg)
#pragma unroll
                for (int cg = 0; cg < 4; ++cg)
                    acc[rg][cg] = __builtin_amdgcn_mfma_f32_16x16x32_bf16(
                        afr[rg], bfr[kg][cg], acc[rg][cg], 0, 0, 0);
        }
        if (PASS == 0) {
#pragma unroll
            for (int rg = 0; rg < 4; ++rg) {
#pragma unroll
                for (int r = 0; r < 4; ++r) {
                    float se = __expf(acc[rg][0][r]) + __expf(acc[rg][1][r])
                             + __expf(acc[rg][2][r]) + __expf(acc[rg][3][r]);
#pragma unroll
                    for (int s = 1; s < 16; s <<= 1) se += __shfl_xor(se, s);
                    if (lm == 0)
                        stats[(rowbase + rg * 16 + lq * 4 + r) * 500 + chunk] = se;
                }
            }
        } else {
#pragma unroll
            for (int rg = 0; rg < 4; ++rg) {
                const int row = rowbase + rg * 16 + lq * 4;
#pragma unroll
                for (int r = 0; r < 4; ++r) {
                    const float cf = coef[row + r];
                    float* __restrict__ dst = &p_prim[(size_t)(row + r) * VV + colbase + lm];
#pragma unroll
                    for (int cg = 0; cg < 4; ++cg)
                        dst[cg * 16] = cf * __expf(acc[rg][cg][r]);
                }
            }
        }
    }
}

// ---------------------------------------------------------------------------
// K8: combine per-chunk sumexp -> coef = gate0 / total  (deterministic)
// ---------------------------------------------------------------------------
__global__ __launch_bounds__(256) void k_combine(
    const float* __restrict__ stats, const float* __restrict__ gate0_ws,
    float* __restrict__ coef)
{
    const int w = threadIdx.x >> 6, lane = threadIdx.x & 63;
    const int row = blockIdx.x * 4 + w;
    float se = 0.f;
    for (int c = lane; c < 500; c += 64) se += stats[row * 500 + c];
#pragma unroll
    for (int s = 1; s < 64; s <<= 1) se += __shfl_xor(se, s);
    if (lane == 0) coef[row] = gate0_ws[row] / se;
}

// ---------------------------------------------------------------------------
// K9: scatter copy mass into p_prim rows
// ---------------------------------------------------------------------------
__global__ __launch_bounds__(256) void k_scatter(
    const int* __restrict__ tok, const float* __restrict__ copy_mass, float* __restrict__ p_prim)
{
    int i = blockIdx.x * 256 + threadIdx.x;
    if (i >= NB * LL) return;
    int b = i / LL;
    atomicAdd(&p_prim[(size_t)b * VV + tok[i]], copy_mass[i]);
}

// ---------------------------------------------------------------------------
extern "C" void kernel_launch(void* const* d_in, const int* in_sizes, int n_in,
                              void* d_out, int out_size, void* d_ws, size_t ws_size,
                              hipStream_t stream)
{
    const float* x         = (const float*)d_in[0];
    const float* h0        = (const float*)d_in[1];
    const float* c0        = (const float*)d_in[2];
    const float* src_enc   = (const float*)d_in[3];
    const int*   tok       = (const int*)  d_in[4];
    const float* W_ih      = (const float*)d_in[5];
    const float* b_ih      = (const float*)d_in[6];
    const float* W_hh      = (const float*)d_in[7];
    const float* b_hh      = (const float*)d_in[8];
    const float* W_attn    = (const float*)d_in[9];
    const float* W_att_vec = (const float*)d_in[10];
    const float* W_ptr     = (const float*)d_in[11];
    const float* rule_emb  = (const float*)d_in[12];
    const float* W_rule_pr = (const float*)d_in[13];
    const float* prim_emb  = (const float*)d_in[14];
    const float* W_prim_pr = (const float*)d_in[15];
    const float* w_gen     = (const float*)d_in[16];
    const float* b_gen     = (const float*)d_in[17];

    float* out    = (float*)d_out;
    float* o_logp = out;                               // [1024,129]
    float* o_pp   = out + 1024 * 129;                  // [1024,32000]
    float* o_h    = o_pp + (size_t)1024 * 32000;       // [1024,256]
    float* o_c    = o_h + 1024 * 256;                  // [1024,256]
    float* o_att  = o_c + 1024 * 256;                  // [1024,256]

    float* wsf      = (float*)d_ws;
    float* ws_ctx   = wsf;                     // 262144
    float* ws_hW    = ws_ctx   + 262144;       // 262144
    float* ws_rp    = ws_hW    + 262144;       // 33280
    float* ws_gate  = ws_rp    + 33280;        // 1024
    float* ws_cm    = ws_gate  + 1024;         // 102400
    float* ws_coef  = ws_cm    + 102400;       // 1024
    float* ws_stats = ws_coef  + 1024;         // 512000 (1024*500)
    u16*   ws_attbf = (u16*)(ws_stats + 512000);       // 131072 u16 = 65536 f
    u16*   ws_primbf= (u16*)(ws_stats + 512000 + 65536); // 4096000 u16
    // total ~ 13.2 MB

    k_conv<<<dim3(2000), 256, 0, stream>>>(prim_emb, ws_primbf);
    k_lstm<<<dim3(16, 16), 256, 0, stream>>>(x, h0, c0, W_ih, b_ih, W_hh, b_hh, o_h, o_c);
    k_hw<<<dim3(16, 4), 256, 0, stream>>>(o_h, W_attn, ws_hW);
    k_attn<<<dim3(1024), 256, 0, stream>>>(src_enc, ws_hW, ws_ctx);
    k_attvec<<<dim3(16, 4), 256, 0, stream>>>(o_h, ws_ctx, W_att_vec, o_att);
    k_ruleproj<<<dim3(129), 256, 0, stream>>>(rule_emb, W_rule_pr, ws_rp);
    k_readout<<<dim3(1024), 256, 0, stream>>>(o_att, src_enc, ws_rp, W_ptr, W_prim_pr,
                                              w_gen, b_gen, o_logp, ws_attbf, ws_gate, ws_cm);
    k_prim<0><<<dim3(250, 4), 256, 0, stream>>>(ws_attbf, ws_primbf, nullptr, ws_stats, nullptr);
    k_combine<<<dim3(256), 256, 0, stream>>>(ws_stats, ws_gate, ws_coef);
    k_prim<1><<<dim3(250, 4), 256, 0, stream>>>(ws_attbf, ws_primbf, ws_coef, nullptr, o_pp);
    k_scatter<<<dim3(400), 256, 0, stream>>>(tok, ws_cm, o_pp);
}

// Round 4
// 267.430 us; speedup vs baseline: 1.3782x; 1.1034x over previous
//
#include <hip/hip_runtime.h>
#include <hip/hip_bf16.h>
#include <math.h>

#define NB   1024
#define LL   100
#define DD   256
#define DINN 704
#define VV   32000
#define RR   129
#define KAV  512

typedef float f32x4 __attribute__((ext_vector_type(4)));
typedef short s16x8 __attribute__((ext_vector_type(8)));
typedef unsigned short u16;

__device__ __forceinline__ float sigf(float x) { return 1.0f / (1.0f + __expf(-x)); }

__device__ __forceinline__ u16 f2bf(float f) {
    unsigned int u = __float_as_uint(f);
    u += 0x7fffu + ((u >> 16) & 1u);
    return (u16)(u >> 16);
}
__device__ __forceinline__ float bf2f(u16 s) {
    return __uint_as_float(((unsigned int)s) << 16);
}

// ---------------------------------------------------------------------------
// K1: LSTM cell. 32-row x 64-gate-col tiles, grid (32,16) = 512 blocks
// (2 blocks/CU vs 1 before — staging latency now overlapped across blocks).
// ---------------------------------------------------------------------------
__global__ __launch_bounds__(256) void k_lstm(
    const float* __restrict__ x, const float* __restrict__ h0, const float* __restrict__ c0,
    const float* __restrict__ W_ih, const float* __restrict__ b_ih,
    const float* __restrict__ W_hh, const float* __restrict__ b_hh,
    float* __restrict__ out_h, float* __restrict__ out_c)
{
    __shared__ __align__(16) float As[16][36];
    __shared__ __align__(16) float Bs[16][68];
    __shared__ __align__(16) float gsm[32][68];
    const int t = threadIdx.x;
    const int row0 = blockIdx.x * 32;
    const int dg = blockIdx.y;            // 0..15 : which 16-wide d group
    const int tr = t >> 4, tc = t & 15;   // tr: 2-row group, tc: 4-col group
    float acc[2][4] = {};

    for (int kt = 0; kt < 60; ++kt) {
        const float* __restrict__ Asrc;
        const float* __restrict__ Bsrc;
        int lda, kb;
        if (kt < 44) { Asrc = x;  Bsrc = W_ih; lda = DINN; kb = kt * 16; }
        else         { Asrc = h0; Bsrc = W_hh; lda = DD;   kb = (kt - 44) * 16; }
        __syncthreads();
#pragma unroll
        for (int p = 0; p < 2; ++p) {          // A: 32x16
            int e = t + p * 256;
            int r = e >> 4, kk = e & 15;
            As[kk][r] = Asrc[(row0 + r) * lda + kb + kk];
        }
#pragma unroll
        for (int p = 0; p < 4; ++p) {          // B: 64x16
            int e = t + p * 256;
            int r = e >> 4, kk = e & 15;
            int n = ((r >> 4) << 8) + dg * 16 + (r & 15);
            Bs[kk][r] = Bsrc[n * lda + kb + kk];
        }
        __syncthreads();
#pragma unroll
        for (int kk = 0; kk < 16; ++kk) {
            float a0 = As[kk][tr * 2], a1 = As[kk][tr * 2 + 1];
            f32x4 b = *reinterpret_cast<const f32x4*>(&Bs[kk][tc * 4]);
#pragma unroll
            for (int i = 0; i < 4; ++i) {
                acc[0][i] = fmaf(a0, b[i], acc[0][i]);
                acc[1][i] = fmaf(a1, b[i], acc[1][i]);
            }
        }
    }
    __syncthreads();
#pragma unroll
    for (int j = 0; j < 2; ++j)
#pragma unroll
        for (int i = 0; i < 4; ++i)
            gsm[tr * 2 + j][tc * 4 + i] = acc[j][i];
    __syncthreads();

#pragma unroll
    for (int p = 0; p < 2; ++p) {
        int item = t + p * 256;          // 32 rows x 16 d
        int r = item >> 4, di = item & 15;
        int dcol = dg * 16 + di;
        float iv = gsm[r][di]      + b_ih[dcol]          + b_hh[dcol];
        float fv = gsm[r][16 + di] + b_ih[DD + dcol]     + b_hh[DD + dcol];
        float gv = gsm[r][32 + di] + b_ih[2 * DD + dcol] + b_hh[2 * DD + dcol];
        float ov = gsm[r][48 + di] + b_ih[3 * DD + dcol] + b_hh[3 * DD + dcol];
        float cprev = c0[(row0 + r) * DD + dcol];
        float cc = sigf(fv) * cprev + sigf(iv) * tanhf(gv);
        float hh = sigf(ov) * tanhf(cc);
        out_c[(row0 + r) * DD + dcol] = cc;
        out_h[(row0 + r) * DD + dcol] = hh;
    }
}

// ---------------------------------------------------------------------------
// K3: per-row attention, with hW = h@W_attn computed inline (W_attn is
// L2-resident 256 KB; kills the separate under-occupied k_hw dispatch).
// ---------------------------------------------------------------------------
__global__ __launch_bounds__(256) void k_attn(
    const float* __restrict__ src_enc, const float* __restrict__ h,
    const float* __restrict__ W_attn, float* __restrict__ ctx_out)
{
    __shared__ __align__(16) u16 enc_s[LL * DD];
    __shared__ __align__(16) float h_s[DD];
    __shared__ __align__(16) float hw_s[DD];
    __shared__ float sc_s[LL];
    __shared__ float al_s[LL];
    const int b = blockIdx.x, t = threadIdx.x;
    const int lane = t & 63, w = t >> 6;

    h_s[t] = h[b * DD + t];
    __syncthreads();
    {   // hW[d=t] = sum_e h[e] * W_attn[e*DD + t]   (coalesced in t)
        float a0 = 0.f, a1 = 0.f, a2 = 0.f, a3 = 0.f;
        const float* __restrict__ wp = W_attn + t;
#pragma unroll 4
        for (int e = 0; e < DD; e += 4) {
            a0 = fmaf(h_s[e],     wp[(e)     * DD], a0);
            a1 = fmaf(h_s[e + 1], wp[(e + 1) * DD], a1);
            a2 = fmaf(h_s[e + 2], wp[(e + 2) * DD], a2);
            a3 = fmaf(h_s[e + 3], wp[(e + 3) * DD], a3);
        }
        hw_s[t] = (a0 + a1) + (a2 + a3);
    }
    __syncthreads();

    const float* __restrict__ enc = src_enc + (size_t)b * LL * DD;
    f32x4 hw4 = *reinterpret_cast<const f32x4*>(&hw_s[lane * 4]);

    for (int l = w; l < LL; l += 4) {
        f32x4 ev = *reinterpret_cast<const f32x4*>(&enc[l * DD + lane * 4]);
        float pr = hw4[0] * ev[0] + hw4[1] * ev[1] + hw4[2] * ev[2] + hw4[3] * ev[3];
#pragma unroll
        for (int m = 1; m < 64; m <<= 1) pr += __shfl_xor(pr, m);
        if (lane == 0) sc_s[l] = pr;
        u16* es = &enc_s[l * DD + lane * 4];
        es[0] = f2bf(ev[0]); es[1] = f2bf(ev[1]); es[2] = f2bf(ev[2]); es[3] = f2bf(ev[3]);
    }
    __syncthreads();
    if (w == 0) {
        float v0 = sc_s[lane];
        float v1 = (lane + 64 < LL) ? sc_s[lane + 64] : -1e30f;
        float m = fmaxf(v0, v1);
#pragma unroll
        for (int s = 1; s < 64; s <<= 1) m = fmaxf(m, __shfl_xor(m, s));
        float e0 = __expf(v0 - m);
        float e1 = (lane + 64 < LL) ? __expf(v1 - m) : 0.f;
        float ssum = e0 + e1;
#pragma unroll
        for (int s = 1; s < 64; s <<= 1) ssum += __shfl_xor(ssum, s);
        float inv = 1.f / ssum;
        al_s[lane] = e0 * inv;
        if (lane + 64 < LL) al_s[lane + 64] = e1 * inv;
    }
    __syncthreads();
    float accv = 0.f;
    for (int l = 0; l < LL; ++l) accv += al_s[l] * bf2f(enc_s[l * DD + t]);
    ctx_out[b * DD + t] = accv;
}

// ---------------------------------------------------------------------------
// K4: att = tanh(concat(h, ctx) @ W_att_vec^T), 32-row tiles, grid (32,4)
// ---------------------------------------------------------------------------
__global__ __launch_bounds__(256) void k_attvec(
    const float* __restrict__ h, const float* __restrict__ ctx,
    const float* __restrict__ W_att_vec, float* __restrict__ att_out)
{
    __shared__ __align__(16) float As[16][36];
    __shared__ __align__(16) float Bs[16][68];
    const int t = threadIdx.x;
    const int row0 = blockIdx.x * 32;
    const int col0 = blockIdx.y * 64;
    const int tr = t >> 4, tc = t & 15;
    float acc[2][4] = {};
    for (int kt = 0; kt < 32; ++kt) {
        const float* __restrict__ Asrc = (kt < 16) ? h : ctx;
        int kb = (kt < 16) ? kt * 16 : (kt - 16) * 16;
        int kg = kt * 16;
        __syncthreads();
#pragma unroll
        for (int p = 0; p < 2; ++p) {
            int e = t + p * 256;
            int r = e >> 4, kk = e & 15;
            As[kk][r] = Asrc[(row0 + r) * DD + kb + kk];
        }
#pragma unroll
        for (int p = 0; p < 4; ++p) {
            int e = t + p * 256;
            int r = e >> 4, kk = e & 15;
            Bs[kk][r] = W_att_vec[(col0 + r) * KAV + kg + kk];
        }
        __syncthreads();
#pragma unroll
        for (int kk = 0; kk < 16; ++kk) {
            float a0 = As[kk][tr * 2], a1 = As[kk][tr * 2 + 1];
            f32x4 b = *reinterpret_cast<const f32x4*>(&Bs[kk][tc * 4]);
#pragma unroll
            for (int i = 0; i < 4; ++i) {
                acc[0][i] = fmaf(a0, b[i], acc[0][i]);
                acc[1][i] = fmaf(a1, b[i], acc[1][i]);
            }
        }
    }
#pragma unroll
    for (int j = 0; j < 2; ++j)
#pragma unroll
        for (int i = 0; i < 4; ++i)
            att_out[(row0 + tr * 2 + j) * DD + col0 + tc * 4 + i] = tanhf(acc[j][i]);
}

// ---------------------------------------------------------------------------
// K6: per-row readouts. (unchanged from R3)
// ---------------------------------------------------------------------------
__global__ __launch_bounds__(256) void k_readout(
    const float* __restrict__ att, const float* __restrict__ src_enc,
    const float* __restrict__ rule_proj, const float* __restrict__ W_ptr,
    const float* __restrict__ W_prim_proj, const float* __restrict__ w_gen,
    const float* __restrict__ b_gen,
    float* __restrict__ log_p_rule, u16* __restrict__ att_bf,
    float* __restrict__ gate0_ws, float* __restrict__ copy_mass)
{
    __shared__ __align__(16) float att_s[DD];
    __shared__ __align__(16) float atw_s[DD];
    __shared__ float red_s[RR];
    __shared__ float sc_s[LL];
    __shared__ float gl_s[2];
    __shared__ float mS[2];
    const int b = blockIdx.x, t = threadIdx.x;
    const int lane = t & 63, w = t >> 6;
    att_s[t] = att[b * DD + t];
    __syncthreads();

    if (t < RR) {
        float acc = 0.f;
        const float* __restrict__ rp = &rule_proj[t * DD];
        for (int d = 0; d < DD; d += 4) {
            f32x4 r4 = *reinterpret_cast<const f32x4*>(&rp[d]);
            f32x4 a4 = *reinterpret_cast<const f32x4*>(&att_s[d]);
            acc += r4[0] * a4[0] + r4[1] * a4[1] + r4[2] * a4[2] + r4[3] * a4[3];
        }
        red_s[t] = acc;
    }
    {
        float aw = 0.f;
        for (int d = 0; d < DD; ++d) aw += att_s[d] * W_ptr[d * DD + t];
        atw_s[t] = aw;
    }
    if (t < 128) {
        float ap = 0.f;
        for (int d = 0; d < DD; ++d) ap += att_s[d] * W_prim_proj[d * 128 + t];
        att_bf[b * 128 + t] = f2bf(ap);
    }
    if (w < 2) {
        f32x4 a4 = *reinterpret_cast<const f32x4*>(&att_s[lane * 4]);
        f32x4 g4 = *reinterpret_cast<const f32x4*>(&w_gen[w * DD + lane * 4]);
        float p = a4[0] * g4[0] + a4[1] * g4[1] + a4[2] * g4[2] + a4[3] * g4[3];
#pragma unroll
        for (int s = 1; s < 64; s <<= 1) p += __shfl_xor(p, s);
        if (lane == 0) gl_s[w] = p + b_gen[w];
    }
    __syncthreads();

    if (w == 0) {
        float v0 = red_s[lane];
        float v1 = red_s[lane + 64];
        float v2 = (lane == 0) ? red_s[128] : -1e30f;
        float m = fmaxf(fmaxf(v0, v1), v2);
#pragma unroll
        for (int s = 1; s < 64; s <<= 1) m = fmaxf(m, __shfl_xor(m, s));
        float ssum = __expf(v0 - m) + __expf(v1 - m) + ((lane == 0) ? __expf(v2 - m) : 0.f);
#pragma unroll
        for (int s = 1; s < 64; s <<= 1) ssum += __shfl_xor(ssum, s);
        if (lane == 0) { mS[0] = m; mS[1] = logf(ssum); }
    }
    __syncthreads();
    if (t < RR) log_p_rule[b * RR + t] = red_s[t] - mS[0] - mS[1];

    float g0 = gl_s[0], g1 = gl_s[1];
    float gm = fmaxf(g0, g1);
    float e0 = __expf(g0 - gm), e1 = __expf(g1 - gm);
    float gate1 = e1 / (e0 + e1);
    if (t == 0) gate0_ws[b] = e0 / (e0 + e1);

    const float* __restrict__ enc = src_enc + (size_t)b * LL * DD;
    f32x4 aw4 = *reinterpret_cast<const f32x4*>(&atw_s[lane * 4]);
    for (int l = w; l < LL; l += 4) {
        f32x4 ev = *reinterpret_cast<const f32x4*>(&enc[l * DD + lane * 4]);
        float pr = aw4[0] * ev[0] + aw4[1] * ev[1] + aw4[2] * ev[2] + aw4[3] * ev[3];
#pragma unroll
        for (int m = 1; m < 64; m <<= 1) pr += __shfl_xor(pr, m);
        if (lane == 0) sc_s[l] = pr;
    }
    __syncthreads();
    if (w == 0) {
        float v0 = sc_s[lane];
        float v1 = (lane + 64 < LL) ? sc_s[lane + 64] : -1e30f;
        float m = fmaxf(v0, v1);
#pragma unroll
        for (int s = 1; s < 64; s <<= 1) m = fmaxf(m, __shfl_xor(m, s));
        float ee0 = __expf(v0 - m);
        float ee1 = (lane + 64 < LL) ? __expf(v1 - m) : 0.f;
        float ssum = ee0 + ee1;
#pragma unroll
        for (int s = 1; s < 64; s <<= 1) ssum += __shfl_xor(ssum, s);
        float inv = 1.f / ssum;
        copy_mass[b * LL + lane] = gate1 * ee0 * inv;
        if (lane + 64 < LL) copy_mass[b * LL + lane + 64] = gate1 * ee1 * inv;
    }
}

// ---------------------------------------------------------------------------
// K-conv: prim_emb fp32 -> bf16 (32000x128); first 129 blocks also compute
// rule_proj[r] = rule_emb[r] @ W_rule_proj^T (fused, saves a dispatch).
// ---------------------------------------------------------------------------
__global__ __launch_bounds__(256) void k_conv(
    const float* __restrict__ src, u16* __restrict__ dst,
    const float* __restrict__ rule_emb, const float* __restrict__ W_rule_proj,
    float* __restrict__ rule_proj)
{
    __shared__ float re_s[128];
    const int bx = blockIdx.x, t = threadIdx.x;
    if (bx < RR && t < 128) re_s[t] = rule_emb[bx * 128 + t];

    int i = (bx * 256 + t) * 8;
    f32x4 a = *reinterpret_cast<const f32x4*>(&src[i]);
    f32x4 b = *reinterpret_cast<const f32x4*>(&src[i + 4]);
    s16x8 r;
    r[0] = (short)f2bf(a[0]); r[1] = (short)f2bf(a[1]);
    r[2] = (short)f2bf(a[2]); r[3] = (short)f2bf(a[3]);
    r[4] = (short)f2bf(b[0]); r[5] = (short)f2bf(b[1]);
    r[6] = (short)f2bf(b[2]); r[7] = (short)f2bf(b[3]);
    *reinterpret_cast<s16x8*>(&dst[i]) = r;

    if (bx < RR) {
        __syncthreads();
        float acc = 0.f;
        const float* __restrict__ wr = &W_rule_proj[t * 128];
#pragma unroll 8
        for (int k = 0; k < 128; k += 4) {
            f32x4 w4 = *reinterpret_cast<const f32x4*>(&wr[k]);
            acc += w4[0] * re_s[k] + w4[1] * re_s[k + 1]
                 + w4[2] * re_s[k + 2] + w4[3] * re_s[k + 3];
        }
        rule_proj[bx * DD + t] = acc;
    }
}

// ---------------------------------------------------------------------------
// K7: logits = att_bf @ prim_bf^T via bf16 MFMA, K=128, no max (|logit|<=8).
// OPERANDS SWAPPED vs R3: A=prim (M), B=att (N). D layout (col=lane&15=att
// row, row=(lane>>4)*4+reg = 4 CONSECUTIVE prim cols) -> f32x4 stores in
// pass1, 2-shfl reduce + coalesced stats (chunk-major) in pass0.
// ---------------------------------------------------------------------------
template <int PASS>
__global__ __launch_bounds__(256) void k_prim(
    const u16* __restrict__ att_bf, const u16* __restrict__ prim_bf,
    const float* __restrict__ coef, float* __restrict__ stats, float* __restrict__ p_prim)
{
    const int t = threadIdx.x;
    const int lane = t & 63, w = t >> 6;
    const int lm = lane & 15, lq = lane >> 4;
    const int colbase = blockIdx.x * 128 + (w & 1) * 64;   // prim cols (M)
    const int chunk = colbase >> 6;
    const int rowblk = blockIdx.y * 256;                   // att rows (N)

    s16x8 pfr[4][4];     // [kg][mg], persistent across row iterations
#pragma unroll
    for (int kg = 0; kg < 4; ++kg)
#pragma unroll
        for (int mg = 0; mg < 4; ++mg)
            pfr[kg][mg] = *reinterpret_cast<const s16x8*>(
                &prim_bf[(size_t)(colbase + mg * 16 + lm) * 128 + kg * 32 + lq * 8]);

    for (int it = 0; it < 2; ++it) {
        const int rowbase = rowblk + it * 128 + (w >> 1) * 64;
        f32x4 acc[4][4] = {};   // [mg][ng]
#pragma unroll
        for (int kg = 0; kg < 4; ++kg) {
            s16x8 afr[4];
#pragma unroll
            for (int ng = 0; ng < 4; ++ng)
                afr[ng] = *reinterpret_cast<const s16x8*>(
                    &att_bf[(rowbase + ng * 16 + lm) * 128 + kg * 32 + lq * 8]);
#pragma unroll
            for (int mg = 0; mg < 4; ++mg)
#pragma unroll
                for (int ng = 0; ng < 4; ++ng)
                    acc[mg][ng] = __builtin_amdgcn_mfma_f32_16x16x32_bf16(
                        pfr[kg][mg], afr[ng], acc[mg][ng], 0, 0, 0);
        }
        if (PASS == 0) {
#pragma unroll
            for (int ng = 0; ng < 4; ++ng) {
                float se = 0.f;
#pragma unroll
                for (int mg = 0; mg < 4; ++mg)
                    se += __expf(acc[mg][ng][0]) + __expf(acc[mg][ng][1])
                        + __expf(acc[mg][ng][2]) + __expf(acc[mg][ng][3]);
                se += __shfl_xor(se, 16);
                se += __shfl_xor(se, 32);
                if (lq == 0)
                    stats[chunk * NB + rowbase + ng * 16 + lm] = se;
            }
        } else {
#pragma unroll
            for (int ng = 0; ng < 4; ++ng) {
                const int arow = rowbase + ng * 16 + lm;
                const float cf = coef[arow];
                float* __restrict__ dst = &p_prim[(size_t)arow * VV + colbase + lq * 4];
#pragma unroll
                for (int mg = 0; mg < 4; ++mg) {
                    f32x4 v;
                    v[0] = cf * __expf(acc[mg][ng][0]);
                    v[1] = cf * __expf(acc[mg][ng][1]);
                    v[2] = cf * __expf(acc[mg][ng][2]);
                    v[3] = cf * __expf(acc[mg][ng][3]);
                    *reinterpret_cast<f32x4*>(&dst[mg * 16]) = v;
                }
            }
        }
    }
}

// ---------------------------------------------------------------------------
// K8: combine chunk-major sumexp -> coef = gate0/total. Coalesced (lane=row).
// ---------------------------------------------------------------------------
__global__ __launch_bounds__(256) void k_combine(
    const float* __restrict__ stats, const float* __restrict__ gate0_ws,
    float* __restrict__ coef)
{
    const int row = blockIdx.x * 256 + threadIdx.x;
    float s0 = 0.f, s1 = 0.f, s2 = 0.f, s3 = 0.f;
    for (int c = 0; c < 500; c += 4) {
        s0 += stats[(c)     * NB + row];
        s1 += stats[(c + 1) * NB + row];
        s2 += stats[(c + 2) * NB + row];
        s3 += stats[(c + 3) * NB + row];
    }
    coef[row] = gate0_ws[row] / ((s0 + s1) + (s2 + s3));
}

// ---------------------------------------------------------------------------
// K9: scatter copy mass into p_prim rows
// ---------------------------------------------------------------------------
__global__ __launch_bounds__(256) void k_scatter(
    const int* __restrict__ tok, const float* __restrict__ copy_mass, float* __restrict__ p_prim)
{
    int i = blockIdx.x * 256 + threadIdx.x;
    if (i >= NB * LL) return;
    int b = i / LL;
    atomicAdd(&p_prim[(size_t)b * VV + tok[i]], copy_mass[i]);
}

// ---------------------------------------------------------------------------
extern "C" void kernel_launch(void* const* d_in, const int* in_sizes, int n_in,
                              void* d_out, int out_size, void* d_ws, size_t ws_size,
                              hipStream_t stream)
{
    const float* x         = (const float*)d_in[0];
    const float* h0        = (const float*)d_in[1];
    const float* c0        = (const float*)d_in[2];
    const float* src_enc   = (const float*)d_in[3];
    const int*   tok       = (const int*)  d_in[4];
    const float* W_ih      = (const float*)d_in[5];
    const float* b_ih      = (const float*)d_in[6];
    const float* W_hh      = (const float*)d_in[7];
    const float* b_hh      = (const float*)d_in[8];
    const float* W_attn    = (const float*)d_in[9];
    const float* W_att_vec = (const float*)d_in[10];
    const float* W_ptr     = (const float*)d_in[11];
    const float* rule_emb  = (const float*)d_in[12];
    const float* W_rule_pr = (const float*)d_in[13];
    const float* prim_emb  = (const float*)d_in[14];
    const float* W_prim_pr = (const float*)d_in[15];
    const float* w_gen     = (const float*)d_in[16];
    const float* b_gen     = (const float*)d_in[17];

    float* out    = (float*)d_out;
    float* o_logp = out;                               // [1024,129]
    float* o_pp   = out + 1024 * 129;                  // [1024,32000]
    float* o_h    = o_pp + (size_t)1024 * 32000;       // [1024,256]
    float* o_c    = o_h + 1024 * 256;                  // [1024,256]
    float* o_att  = o_c + 1024 * 256;                  // [1024,256]

    float* wsf      = (float*)d_ws;
    float* ws_ctx   = wsf;                     // 262144
    float* ws_rp    = ws_ctx   + 262144;       // 33280
    float* ws_gate  = ws_rp    + 33280;        // 1024
    float* ws_cm    = ws_gate  + 1024;         // 102400
    float* ws_coef  = ws_cm    + 102400;       // 1024
    float* ws_stats = ws_coef  + 1024;         // 512000 (500 chunks x 1024 rows)
    u16*   ws_attbf = (u16*)(ws_stats + 512000);         // 131072 u16
    u16*   ws_primbf= (u16*)(ws_stats + 512000 + 65536); // 4096000 u16
    // total ~ 12.2 MB

    k_conv<<<dim3(2000), 256, 0, stream>>>(prim_emb, ws_primbf, rule_emb, W_rule_pr, ws_rp);
    k_lstm<<<dim3(32, 16), 256, 0, stream>>>(x, h0, c0, W_ih, b_ih, W_hh, b_hh, o_h, o_c);
    k_attn<<<dim3(1024), 256, 0, stream>>>(src_enc, o_h, W_attn, ws_ctx);
    k_attvec<<<dim3(32, 4), 256, 0, stream>>>(o_h, ws_ctx, W_att_vec, o_att);
    k_readout<<<dim3(1024), 256, 0, stream>>>(o_att, src_enc, ws_rp, W_ptr, W_prim_pr,
                                              w_gen, b_gen, o_logp, ws_attbf, ws_gate, ws_cm);
    k_prim<0><<<dim3(250, 4), 256, 0, stream>>>(ws_attbf, ws_primbf, nullptr, ws_stats, nullptr);
    k_combine<<<dim3(4), 256, 0, stream>>>(ws_stats, ws_gate, ws_coef);
    k_prim<1><<<dim3(250, 4), 256, 0, stream>>>(ws_attbf, ws_primbf, ws_coef, nullptr, o_pp);
    k_scatter<<<dim3(400), 256, 0, stream>>>(tok, ws_cm, o_pp);
}

// Round 6
// 249.800 us; speedup vs baseline: 1.4755x; 1.0706x over previous
//
#include <hip/hip_runtime.h>
#include <hip/hip_bf16.h>
#include <math.h>

#define NB   1024
#define LL   100
#define DD   256
#define DINN 704
#define VV   32000
#define RR   129
#define KAV  512

typedef float f32x4 __attribute__((ext_vector_type(4)));
typedef float f32x2 __attribute__((ext_vector_type(2)));
typedef short s16x8 __attribute__((ext_vector_type(8)));
typedef unsigned short u16;

__device__ __forceinline__ float sigf(float x) { return 1.0f / (1.0f + __expf(-x)); }

__device__ __forceinline__ u16 f2bf(float f) {
    unsigned int u = __float_as_uint(f);
    u += 0x7fffu + ((u >> 16) & 1u);
    return (u16)(u >> 16);
}

// ---------------------------------------------------------------------------
// K1: LSTM cell. 32-row x 64-gate-col tiles, grid (32,16) = 512 blocks.
// ---------------------------------------------------------------------------
__global__ __launch_bounds__(256) void k_lstm(
    const float* __restrict__ x, const float* __restrict__ h0, const float* __restrict__ c0,
    const float* __restrict__ W_ih, const float* __restrict__ b_ih,
    const float* __restrict__ W_hh, const float* __restrict__ b_hh,
    float* __restrict__ out_h, float* __restrict__ out_c)
{
    __shared__ __align__(16) float As[16][36];
    __shared__ __align__(16) float Bs[16][68];
    __shared__ __align__(16) float gsm[32][68];
    const int t = threadIdx.x;
    const int row0 = blockIdx.x * 32;
    const int dg = blockIdx.y;
    const int tr = t >> 4, tc = t & 15;
    float acc[2][4] = {};

    for (int kt = 0; kt < 60; ++kt) {
        const float* __restrict__ Asrc;
        const float* __restrict__ Bsrc;
        int lda, kb;
        if (kt < 44) { Asrc = x;  Bsrc = W_ih; lda = DINN; kb = kt * 16; }
        else         { Asrc = h0; Bsrc = W_hh; lda = DD;   kb = (kt - 44) * 16; }
        __syncthreads();
#pragma unroll
        for (int p = 0; p < 2; ++p) {
            int e = t + p * 256;
            int r = e >> 4, kk = e & 15;
            As[kk][r] = Asrc[(row0 + r) * lda + kb + kk];
        }
#pragma unroll
        for (int p = 0; p < 4; ++p) {
            int e = t + p * 256;
            int r = e >> 4, kk = e & 15;
            int n = ((r >> 4) << 8) + dg * 16 + (r & 15);
            Bs[kk][r] = Bsrc[n * lda + kb + kk];
        }
        __syncthreads();
#pragma unroll
        for (int kk = 0; kk < 16; ++kk) {
            float a0 = As[kk][tr * 2], a1 = As[kk][tr * 2 + 1];
            f32x4 b = *reinterpret_cast<const f32x4*>(&Bs[kk][tc * 4]);
#pragma unroll
            for (int i = 0; i < 4; ++i) {
                acc[0][i] = fmaf(a0, b[i], acc[0][i]);
                acc[1][i] = fmaf(a1, b[i], acc[1][i]);
            }
        }
    }
    __syncthreads();
#pragma unroll
    for (int j = 0; j < 2; ++j)
#pragma unroll
        for (int i = 0; i < 4; ++i)
            gsm[tr * 2 + j][tc * 4 + i] = acc[j][i];
    __syncthreads();

#pragma unroll
    for (int p = 0; p < 2; ++p) {
        int item = t + p * 256;
        int r = item >> 4, di = item & 15;
        int dcol = dg * 16 + di;
        float iv = gsm[r][di]      + b_ih[dcol]          + b_hh[dcol];
        float fv = gsm[r][16 + di] + b_ih[DD + dcol]     + b_hh[DD + dcol];
        float gv = gsm[r][32 + di] + b_ih[2 * DD + dcol] + b_hh[2 * DD + dcol];
        float ov = gsm[r][48 + di] + b_ih[3 * DD + dcol] + b_hh[3 * DD + dcol];
        float cprev = c0[(row0 + r) * DD + dcol];
        float cc = sigf(fv) * cprev + sigf(iv) * tanhf(gv);
        float hh = sigf(ov) * tanhf(cc);
        out_c[(row0 + r) * DD + dcol] = cc;
        out_h[(row0 + r) * DD + dcol] = hh;
    }
}

// ---------------------------------------------------------------------------
// K-conv: blocks 0..1999: prim_emb fp32->bf16 (blocks <129 also rule_proj).
// Blocks 2000..2031: transpose W_att_vec [256][512] -> wt [512][256].
// ---------------------------------------------------------------------------
__global__ __launch_bounds__(256) void k_conv(
    const float* __restrict__ src, u16* __restrict__ dst,
    const float* __restrict__ rule_emb, const float* __restrict__ W_rule_proj,
    float* __restrict__ rule_proj,
    const float* __restrict__ W_att_vec, float* __restrict__ wt)
{
    __shared__ float re_s[128];
    __shared__ __align__(16) float tile[64][65];
    const int bx = blockIdx.x, t = threadIdx.x;

    if (bx >= 2000) {
        const int id = bx - 2000;        // 0..31
        const int c0 = (id >> 3) * 64;   // att-col tile
        const int k0 = (id & 7) * 64;    // k tile
        const int r = t >> 6, cc = t & 63;
#pragma unroll
        for (int p = 0; p < 16; ++p)
            tile[r + p * 4][cc] = W_att_vec[(c0 + r + p * 4) * KAV + k0 + cc];
        __syncthreads();
#pragma unroll
        for (int p = 0; p < 16; ++p)
            wt[(k0 + r + p * 4) * DD + c0 + cc] = tile[cc][r + p * 4];
        return;
    }

    if (bx < RR && t < 128) re_s[t] = rule_emb[bx * 128 + t];

    int i = (bx * 256 + t) * 8;
    f32x4 a = *reinterpret_cast<const f32x4*>(&src[i]);
    f32x4 b = *reinterpret_cast<const f32x4*>(&src[i + 4]);
    s16x8 r;
    r[0] = (short)f2bf(a[0]); r[1] = (short)f2bf(a[1]);
    r[2] = (short)f2bf(a[2]); r[3] = (short)f2bf(a[3]);
    r[4] = (short)f2bf(b[0]); r[5] = (short)f2bf(b[1]);
    r[6] = (short)f2bf(b[2]); r[7] = (short)f2bf(b[3]);
    *reinterpret_cast<s16x8*>(&dst[i]) = r;

    if (bx < RR) {
        __syncthreads();
        float acc = 0.f;
        const float* __restrict__ wr = &W_rule_proj[t * 128];
#pragma unroll 8
        for (int k = 0; k < 128; k += 4) {
            f32x4 w4 = *reinterpret_cast<const f32x4*>(&wr[k]);
            acc += w4[0] * re_s[k] + w4[1] * re_s[k + 1]
                 + w4[2] * re_s[k + 2] + w4[3] * re_s[k + 3];
        }
        rule_proj[bx * DD + t] = acc;
    }
}

// ---------------------------------------------------------------------------
// K-fused: per-b attention + att-vec + all readouts in one kernel.
// Every wave-split matvec follows the phase-1 pattern: wave w owns k-slice,
// its 64 lanes cover ALL output columns; partials combined through LDS.
// ---------------------------------------------------------------------------
__global__ __launch_bounds__(256) void k_fused(
    const float* __restrict__ src_enc, const float* __restrict__ h,
    const float* __restrict__ W_attn, const float* __restrict__ Wt,
    const float* __restrict__ rule_proj, const float* __restrict__ W_ptr,
    const float* __restrict__ W_prim_proj, const float* __restrict__ w_gen,
    const float* __restrict__ b_gen,
    float* __restrict__ att_out, float* __restrict__ log_p_rule,
    u16* __restrict__ att_bf, float* __restrict__ gate0_ws,
    float* __restrict__ copy_mass)
{
    __shared__ __align__(16) float hc_s[2 * DD];     // [h | ctx]
    __shared__ __align__(16) float att_s[DD];
    __shared__ __align__(16) float part[4][DD];
    __shared__ __align__(16) float partp[4][128];
    __shared__ float sc_s[LL];
    __shared__ float al_s[LL];
    __shared__ float red_s[RR];
    __shared__ float gl_s[2];
    __shared__ float mS[2];

    const int b = blockIdx.x, t = threadIdx.x;
    const int lane = t & 63, w = t >> 6;
    const float* __restrict__ enc = src_enc + (size_t)b * LL * DD;

    hc_s[t] = h[b * DD + t];
    __syncthreads();

    // ---- phase 1: hW = h @ W_attn, wave w: k-slice, lanes: all 256 cols ----
    {
        f32x4 p = {0.f, 0.f, 0.f, 0.f};
        const int e0 = w * 64;
#pragma unroll 4
        for (int e = e0; e < e0 + 64; ++e) {
            float hv = hc_s[e];
            f32x4 wv = *reinterpret_cast<const f32x4*>(&W_attn[e * DD + lane * 4]);
            p[0] = fmaf(hv, wv[0], p[0]); p[1] = fmaf(hv, wv[1], p[1]);
            p[2] = fmaf(hv, wv[2], p[2]); p[3] = fmaf(hv, wv[3], p[3]);
        }
        *reinterpret_cast<f32x4*>(&part[w][lane * 4]) = p;
    }
    __syncthreads();
    f32x4 hw4;
    {
        f32x4 p0 = *reinterpret_cast<const f32x4*>(&part[0][lane * 4]);
        f32x4 p1 = *reinterpret_cast<const f32x4*>(&part[1][lane * 4]);
        f32x4 p2 = *reinterpret_cast<const f32x4*>(&part[2][lane * 4]);
        f32x4 p3 = *reinterpret_cast<const f32x4*>(&part[3][lane * 4]);
        hw4[0] = (p0[0] + p1[0]) + (p2[0] + p3[0]);
        hw4[1] = (p0[1] + p1[1]) + (p2[1] + p3[1]);
        hw4[2] = (p0[2] + p1[2]) + (p2[2] + p3[2]);
        hw4[3] = (p0[3] + p1[3]) + (p2[3] + p3[3]);
    }

    // ---- phase 2: attention scores (enc from HBM) ----
    for (int l = w; l < LL; l += 4) {
        f32x4 ev = *reinterpret_cast<const f32x4*>(&enc[l * DD + lane * 4]);
        float pr = hw4[0] * ev[0] + hw4[1] * ev[1] + hw4[2] * ev[2] + hw4[3] * ev[3];
#pragma unroll
        for (int m = 1; m < 64; m <<= 1) pr += __shfl_xor(pr, m);
        if (lane == 0) sc_s[l] = pr;
    }
    __syncthreads();
    if (w == 0) {
        float v0 = sc_s[lane];
        float v1 = (lane + 64 < LL) ? sc_s[lane + 64] : -1e30f;
        float m = fmaxf(v0, v1);
#pragma unroll
        for (int s = 1; s < 64; s <<= 1) m = fmaxf(m, __shfl_xor(m, s));
        float e0 = __expf(v0 - m);
        float e1 = (lane + 64 < LL) ? __expf(v1 - m) : 0.f;
        float ssum = e0 + e1;
#pragma unroll
        for (int s = 1; s < 64; s <<= 1) ssum += __shfl_xor(ssum, s);
        float inv = 1.f / ssum;
        al_s[lane] = e0 * inv;
        if (lane + 64 < LL) al_s[lane + 64] = e1 * inv;
    }
    __syncthreads();

    // ---- phase 3: ctx[t] = sum_l alpha[l]*enc[l][t] -> hc_s[256+t] ----
    {
        float a0 = 0.f, a1 = 0.f, a2 = 0.f, a3 = 0.f;
        for (int l = 0; l < LL; l += 4) {
            a0 = fmaf(al_s[l],     enc[(l)     * DD + t], a0);
            a1 = fmaf(al_s[l + 1], enc[(l + 1) * DD + t], a1);
            a2 = fmaf(al_s[l + 2], enc[(l + 2) * DD + t], a2);
            a3 = fmaf(al_s[l + 3], enc[(l + 3) * DD + t], a3);
        }
        hc_s[DD + t] = (a0 + a1) + (a2 + a3);
    }
    __syncthreads();

    // ---- phase 4: att = tanh(cat(h,ctx) @ W_att_vec^T) via transposed Wt.
    // wave w: k in [128w,128w+128); lanes cover all 256 att cols. ----
    {
        f32x4 p = {0.f, 0.f, 0.f, 0.f};
        const int gk0 = w * 128;
#pragma unroll 4
        for (int kk = 0; kk < 128; ++kk) {
            float cv = hc_s[gk0 + kk];
            f32x4 wv = *reinterpret_cast<const f32x4*>(&Wt[(gk0 + kk) * DD + lane * 4]);
            p[0] = fmaf(cv, wv[0], p[0]); p[1] = fmaf(cv, wv[1], p[1]);
            p[2] = fmaf(cv, wv[2], p[2]); p[3] = fmaf(cv, wv[3], p[3]);
        }
        *reinterpret_cast<f32x4*>(&part[w][lane * 4]) = p;
    }
    __syncthreads();
    {
        float av = (part[0][t] + part[1][t]) + (part[2][t] + part[3][t]);
        av = tanhf(av);
        att_s[t] = av;
        att_out[b * DD + t] = av;
    }
    __syncthreads();

    // ---- phase 5: readout matvecs (all read att_s) ----
    {   // atW = att @ W_ptr : wave-split e, lanes cover all 256 cols
        f32x4 p = {0.f, 0.f, 0.f, 0.f};
        const int e0 = w * 64;
#pragma unroll 4
        for (int e = e0; e < e0 + 64; ++e) {
            float av = att_s[e];
            f32x4 wv = *reinterpret_cast<const f32x4*>(&W_ptr[e * DD + lane * 4]);
            p[0] = fmaf(av, wv[0], p[0]); p[1] = fmaf(av, wv[1], p[1]);
            p[2] = fmaf(av, wv[2], p[2]); p[3] = fmaf(av, wv[3], p[3]);
        }
        *reinterpret_cast<f32x4*>(&part[w][lane * 4]) = p;
    }
    {   // att_p = att @ W_prim_proj : wave-split e, lanes cover 128 cols
        float p0 = 0.f, p1 = 0.f;
        const int e0 = w * 64;
#pragma unroll 4
        for (int e = e0; e < e0 + 64; ++e) {
            float av = att_s[e];
            f32x2 wv = *reinterpret_cast<const f32x2*>(&W_prim_proj[e * 128 + lane * 2]);
            p0 = fmaf(av, wv[0], p0);
            p1 = fmaf(av, wv[1], p1);
        }
        partp[w][lane * 2]     = p0;
        partp[w][lane * 2 + 1] = p1;
    }
    if (t < RR) {   // rule logits: per-thread contiguous row dot (L2-resident)
        float acc = 0.f;
        const float* __restrict__ rp = &rule_proj[t * DD];
#pragma unroll 4
        for (int d = 0; d < DD; d += 4) {
            f32x4 r4 = *reinterpret_cast<const f32x4*>(&rp[d]);
            f32x4 a4 = *reinterpret_cast<const f32x4*>(&att_s[d]);
            acc += r4[0] * a4[0] + r4[1] * a4[1] + r4[2] * a4[2] + r4[3] * a4[3];
        }
        red_s[t] = acc;
    }
    if (w < 2) {    // gate logits
        f32x4 a4 = *reinterpret_cast<const f32x4*>(&att_s[lane * 4]);
        f32x4 g4 = *reinterpret_cast<const f32x4*>(&w_gen[w * DD + lane * 4]);
        float p = a4[0] * g4[0] + a4[1] * g4[1] + a4[2] * g4[2] + a4[3] * g4[3];
#pragma unroll
        for (int s = 1; s < 64; s <<= 1) p += __shfl_xor(p, s);
        if (lane == 0) gl_s[w] = p + b_gen[w];
    }
    __syncthreads();

    // ---- phase 6: combines + rule softmax stats ----
    f32x4 aw4;
    {
        f32x4 p0 = *reinterpret_cast<const f32x4*>(&part[0][lane * 4]);
        f32x4 p1 = *reinterpret_cast<const f32x4*>(&part[1][lane * 4]);
        f32x4 p2 = *reinterpret_cast<const f32x4*>(&part[2][lane * 4]);
        f32x4 p3 = *reinterpret_cast<const f32x4*>(&part[3][lane * 4]);
        aw4[0] = (p0[0] + p1[0]) + (p2[0] + p3[0]);
        aw4[1] = (p0[1] + p1[1]) + (p2[1] + p3[1]);
        aw4[2] = (p0[2] + p1[2]) + (p2[2] + p3[2]);
        aw4[3] = (p0[3] + p1[3]) + (p2[3] + p3[3]);
    }
    if (t < 128) {
        float ap = (partp[0][t] + partp[1][t]) + (partp[2][t] + partp[3][t]);
        att_bf[b * 128 + t] = f2bf(ap);
    }
    if (w == 0) {   // log-softmax stats over 129 rules
        float v0 = red_s[lane];
        float v1 = red_s[lane + 64];
        float v2 = (lane == 0) ? red_s[128] : -1e30f;
        float m = fmaxf(fmaxf(v0, v1), v2);
#pragma unroll
        for (int s = 1; s < 64; s <<= 1) m = fmaxf(m, __shfl_xor(m, s));
        float ssum = __expf(v0 - m) + __expf(v1 - m) + ((lane == 0) ? __expf(v2 - m) : 0.f);
#pragma unroll
        for (int s = 1; s < 64; s <<= 1) ssum += __shfl_xor(ssum, s);
        if (lane == 0) { mS[0] = m; mS[1] = logf(ssum); }
    }
    __syncthreads();
    if (t < RR) log_p_rule[b * RR + t] = red_s[t] - mS[0] - mS[1];

    float g0 = gl_s[0], g1 = gl_s[1];
    float gm = fmaxf(g0, g1);
    float e0g = __expf(g0 - gm), e1g = __expf(g1 - gm);
    float gate1 = e1g / (e0g + e1g);
    if (t == 0) gate0_ws[b] = e0g / (e0g + e1g);

    // ---- phase 7: pointer scores (enc L2/L3 re-read) + copy mass ----
    for (int l = w; l < LL; l += 4) {
        f32x4 ev = *reinterpret_cast<const f32x4*>(&enc[l * DD + lane * 4]);
        float pr = aw4[0] * ev[0] + aw4[1] * ev[1] + aw4[2] * ev[2] + aw4[3] * ev[3];
#pragma unroll
        for (int m = 1; m < 64; m <<= 1) pr += __shfl_xor(pr, m);
        if (lane == 0) sc_s[l] = pr;
    }
    __syncthreads();
    if (w == 0) {
        float v0 = sc_s[lane];
        float v1 = (lane + 64 < LL) ? sc_s[lane + 64] : -1e30f;
        float m = fmaxf(v0, v1);
#pragma unroll
        for (int s = 1; s < 64; s <<= 1) m = fmaxf(m, __shfl_xor(m, s));
        float ee0 = __expf(v0 - m);
        float ee1 = (lane + 64 < LL) ? __expf(v1 - m) : 0.f;
        float ssum = ee0 + ee1;
#pragma unroll
        for (int s = 1; s < 64; s <<= 1) ssum += __shfl_xor(ssum, s);
        float inv = 1.f / ssum;
        copy_mass[b * LL + lane] = gate1 * ee0 * inv;
        if (lane + 64 < LL) copy_mass[b * LL + lane + 64] = gate1 * ee1 * inv;
    }
}

// ---------------------------------------------------------------------------
// K7: logits = prim_bf (M) x att_bf (N) via bf16 MFMA, K=128, no max needed.
// ---------------------------------------------------------------------------
template <int PASS>
__global__ __launch_bounds__(256) void k_prim(
    const u16* __restrict__ att_bf, const u16* __restrict__ prim_bf,
    const float* __restrict__ coef, float* __restrict__ stats, float* __restrict__ p_prim)
{
    const int t = threadIdx.x;
    const int lane = t & 63, w = t >> 6;
    const int lm = lane & 15, lq = lane >> 4;
    const int colbase = blockIdx.x * 128 + (w & 1) * 64;   // prim cols (M)
    const int chunk = colbase >> 6;
    const int rowblk = blockIdx.y * 256;                   // att rows (N)

    s16x8 pfr[4][4];
#pragma unroll
    for (int kg = 0; kg < 4; ++kg)
#pragma unroll
        for (int mg = 0; mg < 4; ++mg)
            pfr[kg][mg] = *reinterpret_cast<const s16x8*>(
                &prim_bf[(size_t)(colbase + mg * 16 + lm) * 128 + kg * 32 + lq * 8]);

    for (int it = 0; it < 2; ++it) {
        const int rowbase = rowblk + it * 128 + (w >> 1) * 64;
        f32x4 acc[4][4] = {};   // [mg][ng]
#pragma unroll
        for (int kg = 0; kg < 4; ++kg) {
            s16x8 afr[4];
#pragma unroll
            for (int ng = 0; ng < 4; ++ng)
                afr[ng] = *reinterpret_cast<const s16x8*>(
                    &att_bf[(rowbase + ng * 16 + lm) * 128 + kg * 32 + lq * 8]);
#pragma unroll
            for (int mg = 0; mg < 4; ++mg)
#pragma unroll
                for (int ng = 0; ng < 4; ++ng)
                    acc[mg][ng] = __builtin_amdgcn_mfma_f32_16x16x32_bf16(
                        pfr[kg][mg], afr[ng], acc[mg][ng], 0, 0, 0);
        }
        if (PASS == 0) {
#pragma unroll
            for (int ng = 0; ng < 4; ++ng) {
                float se = 0.f;
#pragma unroll
                for (int mg = 0; mg < 4; ++mg)
                    se += __expf(acc[mg][ng][0]) + __expf(acc[mg][ng][1])
                        + __expf(acc[mg][ng][2]) + __expf(acc[mg][ng][3]);
                se += __shfl_xor(se, 16);
                se += __shfl_xor(se, 32);
                if (lq == 0)
                    stats[chunk * NB + rowbase + ng * 16 + lm] = se;
            }
        } else {
#pragma unroll
            for (int ng = 0; ng < 4; ++ng) {
                const int arow = rowbase + ng * 16 + lm;
                const float cf = coef[arow];
                float* __restrict__ dst = &p_prim[(size_t)arow * VV + colbase + lq * 4];
#pragma unroll
                for (int mg = 0; mg < 4; ++mg) {
                    f32x4 v;
                    v[0] = cf * __expf(acc[mg][ng][0]);
                    v[1] = cf * __expf(acc[mg][ng][1]);
                    v[2] = cf * __expf(acc[mg][ng][2]);
                    v[3] = cf * __expf(acc[mg][ng][3]);
                    *reinterpret_cast<f32x4*>(&dst[mg * 16]) = v;
                }
            }
        }
    }
}

// ---------------------------------------------------------------------------
// K8: combine chunk-major sumexp -> coef = gate0/total (coalesced).
// ---------------------------------------------------------------------------
__global__ __launch_bounds__(256) void k_combine(
    const float* __restrict__ stats, const float* __restrict__ gate0_ws,
    float* __restrict__ coef)
{
    const int row = blockIdx.x * 256 + threadIdx.x;
    float s0 = 0.f, s1 = 0.f, s2 = 0.f, s3 = 0.f;
    for (int c = 0; c < 500; c += 4) {
        s0 += stats[(c)     * NB + row];
        s1 += stats[(c + 1) * NB + row];
        s2 += stats[(c + 2) * NB + row];
        s3 += stats[(c + 3) * NB + row];
    }
    coef[row] = gate0_ws[row] / ((s0 + s1) + (s2 + s3));
}

// ---------------------------------------------------------------------------
// K9: scatter copy mass into p_prim rows
// ---------------------------------------------------------------------------
__global__ __launch_bounds__(256) void k_scatter(
    const int* __restrict__ tok, const float* __restrict__ copy_mass, float* __restrict__ p_prim)
{
    int i = blockIdx.x * 256 + threadIdx.x;
    if (i >= NB * LL) return;
    int b = i / LL;
    atomicAdd(&p_prim[(size_t)b * VV + tok[i]], copy_mass[i]);
}

// ---------------------------------------------------------------------------
extern "C" void kernel_launch(void* const* d_in, const int* in_sizes, int n_in,
                              void* d_out, int out_size, void* d_ws, size_t ws_size,
                              hipStream_t stream)
{
    const float* x         = (const float*)d_in[0];
    const float* h0        = (const float*)d_in[1];
    const float* c0        = (const float*)d_in[2];
    const float* src_enc   = (const float*)d_in[3];
    const int*   tok       = (const int*)  d_in[4];
    const float* W_ih      = (const float*)d_in[5];
    const float* b_ih      = (const float*)d_in[6];
    const float* W_hh      = (const float*)d_in[7];
    const float* b_hh      = (const float*)d_in[8];
    const float* W_attn    = (const float*)d_in[9];
    const float* W_att_vec = (const float*)d_in[10];
    const float* W_ptr     = (const float*)d_in[11];
    const float* rule_emb  = (const float*)d_in[12];
    const float* W_rule_pr = (const float*)d_in[13];
    const float* prim_emb  = (const float*)d_in[14];
    const float* W_prim_pr = (const float*)d_in[15];
    const float* w_gen     = (const float*)d_in[16];
    const float* b_gen     = (const float*)d_in[17];

    float* out    = (float*)d_out;
    float* o_logp = out;                               // [1024,129]
    float* o_pp   = out + 1024 * 129;                  // [1024,32000]
    float* o_h    = o_pp + (size_t)1024 * 32000;       // [1024,256]
    float* o_c    = o_h + 1024 * 256;                  // [1024,256]
    float* o_att  = o_c + 1024 * 256;                  // [1024,256]

    float* wsf      = (float*)d_ws;
    float* ws_rp    = wsf;                     // 33280
    float* ws_gate  = ws_rp    + 33280;        // 1024
    float* ws_cm    = ws_gate  + 1024;         // 102400
    float* ws_coef  = ws_cm    + 102400;       // 1024
    float* ws_stats = ws_coef  + 1024;         // 512000 (500 chunks x 1024 rows)
    float* ws_wt    = ws_stats + 512000;       // 131072 (W_att_vec^T, 512x256)
    u16*   ws_attbf = (u16*)(ws_wt + 131072);            // 131072 u16
    u16*   ws_primbf= (u16*)(ws_wt + 131072 + 65536);    // 4096000 u16

    k_conv<<<dim3(2032), 256, 0, stream>>>(prim_emb, ws_primbf, rule_emb, W_rule_pr,
                                           ws_rp, W_att_vec, ws_wt);
    k_lstm<<<dim3(32, 16), 256, 0, stream>>>(x, h0, c0, W_ih, b_ih, W_hh, b_hh, o_h, o_c);
    k_fused<<<dim3(1024), 256, 0, stream>>>(src_enc, o_h, W_attn, ws_wt, ws_rp, W_ptr,
                                            W_prim_pr, w_gen, b_gen,
                                            o_att, o_logp, ws_attbf, ws_gate, ws_cm);
    k_prim<0><<<dim3(250, 4), 256, 0, stream>>>(ws_attbf, ws_primbf, nullptr, ws_stats, nullptr);
    k_combine<<<dim3(4), 256, 0, stream>>>(ws_stats, ws_gate, ws_coef);
    k_prim<1><<<dim3(250, 4), 256, 0, stream>>>(ws_attbf, ws_primbf, ws_coef, nullptr, o_pp);
    k_scatter<<<dim3(400), 256, 0, stream>>>(tok, ws_cm, o_pp);
}

// Round 7
// 240.701 us; speedup vs baseline: 1.5312x; 1.0378x over previous
//
#include <hip/hip_runtime.h>
#include <hip/hip_bf16.h>
#include <math.h>

#define NB   1024
#define LL   100
#define DD   256
#define DINN 704
#define VV   32000
#define RR   129
#define KAV  512
#define ROWU 129   // enc LDS row stride in dwords (odd => conflict-free)

typedef float f32x4 __attribute__((ext_vector_type(4)));
typedef float f32x2 __attribute__((ext_vector_type(2)));
typedef short s16x8 __attribute__((ext_vector_type(8)));
typedef unsigned short u16;
typedef unsigned int u32;

__device__ __forceinline__ float sigf(float x) { return 1.0f / (1.0f + __expf(-x)); }

__device__ __forceinline__ u16 f2bf(float f) {
    u32 u = __float_as_uint(f);
    u += 0x7fffu + ((u >> 16) & 1u);
    return (u16)(u >> 16);
}
__device__ __forceinline__ float bf2f(u16 s) {
    return __uint_as_float(((u32)s) << 16);
}

// ---------------------------------------------------------------------------
// K1: LSTM cell. 32-row x 64-gate-col tiles, grid (32,16) = 512 blocks.
// ---------------------------------------------------------------------------
__global__ __launch_bounds__(256) void k_lstm(
    const float* __restrict__ x, const float* __restrict__ h0, const float* __restrict__ c0,
    const float* __restrict__ W_ih, const float* __restrict__ b_ih,
    const float* __restrict__ W_hh, const float* __restrict__ b_hh,
    float* __restrict__ out_h, float* __restrict__ out_c)
{
    __shared__ __align__(16) float As[16][36];
    __shared__ __align__(16) float Bs[16][68];
    __shared__ __align__(16) float gsm[32][68];
    const int t = threadIdx.x;
    const int row0 = blockIdx.x * 32;
    const int dg = blockIdx.y;
    const int tr = t >> 4, tc = t & 15;
    float acc[2][4] = {};

    for (int kt = 0; kt < 60; ++kt) {
        const float* __restrict__ Asrc;
        const float* __restrict__ Bsrc;
        int lda, kb;
        if (kt < 44) { Asrc = x;  Bsrc = W_ih; lda = DINN; kb = kt * 16; }
        else         { Asrc = h0; Bsrc = W_hh; lda = DD;   kb = (kt - 44) * 16; }
        __syncthreads();
#pragma unroll
        for (int p = 0; p < 2; ++p) {
            int e = t + p * 256;
            int r = e >> 4, kk = e & 15;
            As[kk][r] = Asrc[(row0 + r) * lda + kb + kk];
        }
#pragma unroll
        for (int p = 0; p < 4; ++p) {
            int e = t + p * 256;
            int r = e >> 4, kk = e & 15;
            int n = ((r >> 4) << 8) + dg * 16 + (r & 15);
            Bs[kk][r] = Bsrc[n * lda + kb + kk];
        }
        __syncthreads();
#pragma unroll
        for (int kk = 0; kk < 16; ++kk) {
            float a0 = As[kk][tr * 2], a1 = As[kk][tr * 2 + 1];
            f32x4 b = *reinterpret_cast<const f32x4*>(&Bs[kk][tc * 4]);
#pragma unroll
            for (int i = 0; i < 4; ++i) {
                acc[0][i] = fmaf(a0, b[i], acc[0][i]);
                acc[1][i] = fmaf(a1, b[i], acc[1][i]);
            }
        }
    }
    __syncthreads();
#pragma unroll
    for (int j = 0; j < 2; ++j)
#pragma unroll
        for (int i = 0; i < 4; ++i)
            gsm[tr * 2 + j][tc * 4 + i] = acc[j][i];
    __syncthreads();

#pragma unroll
    for (int p = 0; p < 2; ++p) {
        int item = t + p * 256;
        int r = item >> 4, di = item & 15;
        int dcol = dg * 16 + di;
        float iv = gsm[r][di]      + b_ih[dcol]          + b_hh[dcol];
        float fv = gsm[r][16 + di] + b_ih[DD + dcol]     + b_hh[DD + dcol];
        float gv = gsm[r][32 + di] + b_ih[2 * DD + dcol] + b_hh[2 * DD + dcol];
        float ov = gsm[r][48 + di] + b_ih[3 * DD + dcol] + b_hh[3 * DD + dcol];
        float cprev = c0[(row0 + r) * DD + dcol];
        float cc = sigf(fv) * cprev + sigf(iv) * tanhf(gv);
        float hh = sigf(ov) * tanhf(cc);
        out_c[(row0 + r) * DD + dcol] = cc;
        out_h[(row0 + r) * DD + dcol] = hh;
    }
}

// ---------------------------------------------------------------------------
// K-conv: blocks 0..1999: prim_emb fp32->bf16 (blocks <129 also rule_proj).
// Blocks 2000..2031: transpose W_att_vec [256][512] -> wt [512][256].
// ---------------------------------------------------------------------------
__global__ __launch_bounds__(256) void k_conv(
    const float* __restrict__ src, u16* __restrict__ dst,
    const float* __restrict__ rule_emb, const float* __restrict__ W_rule_proj,
    float* __restrict__ rule_proj,
    const float* __restrict__ W_att_vec, float* __restrict__ wt)
{
    __shared__ float re_s[128];
    __shared__ __align__(16) float tile[64][65];
    const int bx = blockIdx.x, t = threadIdx.x;

    if (bx >= 2000) {
        const int id = bx - 2000;
        const int c0 = (id >> 3) * 64;
        const int k0 = (id & 7) * 64;
        const int r = t >> 6, cc = t & 63;
#pragma unroll
        for (int p = 0; p < 16; ++p)
            tile[r + p * 4][cc] = W_att_vec[(c0 + r + p * 4) * KAV + k0 + cc];
        __syncthreads();
#pragma unroll
        for (int p = 0; p < 16; ++p)
            wt[(k0 + r + p * 4) * DD + c0 + cc] = tile[cc][r + p * 4];
        return;
    }

    if (bx < RR && t < 128) re_s[t] = rule_emb[bx * 128 + t];

    int i = (bx * 256 + t) * 8;
    f32x4 a = *reinterpret_cast<const f32x4*>(&src[i]);
    f32x4 b = *reinterpret_cast<const f32x4*>(&src[i + 4]);
    s16x8 r;
    r[0] = (short)f2bf(a[0]); r[1] = (short)f2bf(a[1]);
    r[2] = (short)f2bf(a[2]); r[3] = (short)f2bf(a[3]);
    r[4] = (short)f2bf(b[0]); r[5] = (short)f2bf(b[1]);
    r[6] = (short)f2bf(b[2]); r[7] = (short)f2bf(b[3]);
    *reinterpret_cast<s16x8*>(&dst[i]) = r;

    if (bx < RR) {
        __syncthreads();
        float acc = 0.f;
        const float* __restrict__ wr = &W_rule_proj[t * 128];
#pragma unroll 8
        for (int k = 0; k < 128; k += 4) {
            f32x4 w4 = *reinterpret_cast<const f32x4*>(&wr[k]);
            acc += w4[0] * re_s[k] + w4[1] * re_s[k + 1]
                 + w4[2] * re_s[k + 2] + w4[3] * re_s[k + 3];
        }
        rule_proj[bx * DD + t] = acc;
    }
}

// ---------------------------------------------------------------------------
// K-fused v2: enc staged ONCE in LDS (bf16, row stride 129 dwords).
// Scores & ptr-scores: lane-per-l, no shuffles. Ctx: wave-split l.
// ---------------------------------------------------------------------------
__global__ __launch_bounds__(256) void k_fused(
    const float* __restrict__ src_enc, const float* __restrict__ h,
    const float* __restrict__ W_attn, const float* __restrict__ Wt,
    const float* __restrict__ rule_proj, const float* __restrict__ W_ptr,
    const float* __restrict__ W_prim_proj, const float* __restrict__ w_gen,
    const float* __restrict__ b_gen,
    float* __restrict__ att_out, float* __restrict__ log_p_rule,
    u16* __restrict__ att_bf, float* __restrict__ gate0_ws,
    float* __restrict__ copy_mass)
{
    __shared__ u32 enc_u[LL * ROWU];                 // 51.6 KB bf16 enc
    __shared__ __align__(16) float part[4][DD];      // 4 KB
    __shared__ __align__(16) float partp[4][128];    // 2 KB
    __shared__ __align__(16) float hc_s[2 * DD];     // [h|ctx] -> [att|atW]
    __shared__ __align__(16) float hw_s[DD];
    __shared__ float sc_s[LL];
    __shared__ float al_s[LL];
    __shared__ float red_s[RR];
    __shared__ float gl_s[2];
    __shared__ float mS[2];

    const int b = blockIdx.x, t = threadIdx.x;
    const int lane = t & 63, w = t >> 6;
    const float* __restrict__ enc = src_enc + (size_t)b * LL * DD;

    hc_s[t] = h[b * DD + t];

    // ---- stage enc -> LDS bf16 (25 f32x4 loads/thread, coalesced) ----
#pragma unroll 5
    for (int p = 0; p < 25; ++p) {
        int q = p * 256 + t;
        int l = q >> 6, dq = q & 63;
        f32x4 ev = *reinterpret_cast<const f32x4*>(&enc[l * DD + dq * 4]);
        u32 w0 = (u32)f2bf(ev[0]) | ((u32)f2bf(ev[1]) << 16);
        u32 w1 = (u32)f2bf(ev[2]) | ((u32)f2bf(ev[3]) << 16);
        enc_u[l * ROWU + dq * 2]     = w0;
        enc_u[l * ROWU + dq * 2 + 1] = w1;
    }
    __syncthreads();

    // ---- phase 1: hW = h @ W_attn (wave-split k, lanes cover 256 cols) ----
    {
        f32x4 p = {0.f, 0.f, 0.f, 0.f};
        const int e0 = w * 64;
#pragma unroll 4
        for (int e = e0; e < e0 + 64; ++e) {
            float hv = hc_s[e];
            f32x4 wv = *reinterpret_cast<const f32x4*>(&W_attn[e * DD + lane * 4]);
            p[0] = fmaf(hv, wv[0], p[0]); p[1] = fmaf(hv, wv[1], p[1]);
            p[2] = fmaf(hv, wv[2], p[2]); p[3] = fmaf(hv, wv[3], p[3]);
        }
        *reinterpret_cast<f32x4*>(&part[w][lane * 4]) = p;
    }
    __syncthreads();
    hw_s[t] = (part[0][t] + part[1][t]) + (part[2][t] + part[3][t]);
    __syncthreads();

    // ---- phase 2: scores, lane-per-l, wave pair splits d ----
    {
        const int sl = ((w >> 1) << 6) + lane;       // waves {0,1}: l=lane; {2,3}: 64+lane
        float sp = 0.f;
        if (sl < LL) {
            const u32* __restrict__ rp = enc_u + sl * ROWU + ((w & 1) << 6);
            const float* __restrict__ hp = hw_s + ((w & 1) << 7);
#pragma unroll 16
            for (int k = 0; k < 64; ++k) {
                u32 v = rp[k];
                sp = fmaf(bf2f((u16)v),         hp[2 * k],     sp);
                sp = fmaf(bf2f((u16)(v >> 16)), hp[2 * k + 1], sp);
            }
        }
        part[w][lane] = sp;
    }
    __syncthreads();
    if (t < LL) sc_s[t] = part[(t >> 6) << 1][t & 63] + part[((t >> 6) << 1) + 1][t & 63];
    __syncthreads();

    // ---- softmax over 100 scores (wave 0) ----
    if (w == 0) {
        float v0 = sc_s[lane];
        float v1 = (lane + 64 < LL) ? sc_s[lane + 64] : -1e30f;
        float m = fmaxf(v0, v1);
#pragma unroll
        for (int s = 1; s < 64; s <<= 1) m = fmaxf(m, __shfl_xor(m, s));
        float e0 = __expf(v0 - m);
        float e1 = (lane + 64 < LL) ? __expf(v1 - m) : 0.f;
        float ssum = e0 + e1;
#pragma unroll
        for (int s = 1; s < 64; s <<= 1) ssum += __shfl_xor(ssum, s);
        float inv = 1.f / ssum;
        al_s[lane] = e0 * inv;
        if (lane + 64 < LL) al_s[lane + 64] = e1 * inv;
    }
    __syncthreads();

    // ---- phase 3: ctx, wave-split l (25 each), lanes cover 256 cols ----
    {
        const int l0 = w * 25;
        float c0 = 0.f, c1 = 0.f, c2 = 0.f, c3 = 0.f;
#pragma unroll 5
        for (int li = 0; li < 25; ++li) {
            int l = l0 + li;
            float a = al_s[l];
            u32 v0 = enc_u[l * ROWU + lane * 2];
            u32 v1 = enc_u[l * ROWU + lane * 2 + 1];
            c0 = fmaf(a, bf2f((u16)v0), c0);
            c1 = fmaf(a, bf2f((u16)(v0 >> 16)), c1);
            c2 = fmaf(a, bf2f((u16)v1), c2);
            c3 = fmaf(a, bf2f((u16)(v1 >> 16)), c3);
        }
        f32x4 p; p[0] = c0; p[1] = c1; p[2] = c2; p[3] = c3;
        *reinterpret_cast<f32x4*>(&part[w][lane * 4]) = p;
    }
    __syncthreads();
    hc_s[DD + t] = (part[0][t] + part[1][t]) + (part[2][t] + part[3][t]);
    __syncthreads();

    // ---- phase 4: att = tanh(cat(h,ctx) @ Wt) (wave-split k=512) ----
    {
        f32x4 p = {0.f, 0.f, 0.f, 0.f};
        const int gk0 = w * 128;
#pragma unroll 4
        for (int kk = 0; kk < 128; ++kk) {
            float cv = hc_s[gk0 + kk];
            f32x4 wv = *reinterpret_cast<const f32x4*>(&Wt[(gk0 + kk) * DD + lane * 4]);
            p[0] = fmaf(cv, wv[0], p[0]); p[1] = fmaf(cv, wv[1], p[1]);
            p[2] = fmaf(cv, wv[2], p[2]); p[3] = fmaf(cv, wv[3], p[3]);
        }
        *reinterpret_cast<f32x4*>(&part[w][lane * 4]) = p;
    }
    __syncthreads();
    float att_v = tanhf((part[0][t] + part[1][t]) + (part[2][t] + part[3][t]));
    att_out[b * DD + t] = att_v;
    __syncthreads();          // hc_s[h] dead; reuse
    hc_s[t] = att_v;          // att now in hc_s[0..255]
    __syncthreads();

    // ---- phase 5: readout matvecs ----
    {   // atW = att @ W_ptr
        f32x4 p = {0.f, 0.f, 0.f, 0.f};
        const int e0 = w * 64;
#pragma unroll 4
        for (int e = e0; e < e0 + 64; ++e) {
            float av = hc_s[e];
            f32x4 wv = *reinterpret_cast<const f32x4*>(&W_ptr[e * DD + lane * 4]);
            p[0] = fmaf(av, wv[0], p[0]); p[1] = fmaf(av, wv[1], p[1]);
            p[2] = fmaf(av, wv[2], p[2]); p[3] = fmaf(av, wv[3], p[3]);
        }
        *reinterpret_cast<f32x4*>(&part[w][lane * 4]) = p;
    }
    {   // att_p = att @ W_prim_proj
        float p0 = 0.f, p1 = 0.f;
        const int e0 = w * 64;
#pragma unroll 4
        for (int e = e0; e < e0 + 64; ++e) {
            float av = hc_s[e];
            f32x2 wv = *reinterpret_cast<const f32x2*>(&W_prim_proj[e * 128 + lane * 2]);
            p0 = fmaf(av, wv[0], p0);
            p1 = fmaf(av, wv[1], p1);
        }
        partp[w][lane * 2]     = p0;
        partp[w][lane * 2 + 1] = p1;
    }
    if (t < RR) {   // rule logits
        float acc = 0.f;
        const float* __restrict__ rp = &rule_proj[t * DD];
#pragma unroll 4
        for (int d = 0; d < DD; d += 4) {
            f32x4 r4 = *reinterpret_cast<const f32x4*>(&rp[d]);
            f32x4 a4 = *reinterpret_cast<const f32x4*>(&hc_s[d]);
            acc += r4[0] * a4[0] + r4[1] * a4[1] + r4[2] * a4[2] + r4[3] * a4[3];
        }
        red_s[t] = acc;
    }
    if (w < 2) {    // gate logits
        f32x4 a4 = *reinterpret_cast<const f32x4*>(&hc_s[lane * 4]);
        f32x4 g4 = *reinterpret_cast<const f32x4*>(&w_gen[w * DD + lane * 4]);
        float p = a4[0] * g4[0] + a4[1] * g4[1] + a4[2] * g4[2] + a4[3] * g4[3];
#pragma unroll
        for (int s = 1; s < 64; s <<= 1) p += __shfl_xor(p, s);
        if (lane == 0) gl_s[w] = p + b_gen[w];
    }
    __syncthreads();

    // ---- phase 6: combines + rule log-softmax ----
    hc_s[DD + t] = (part[0][t] + part[1][t]) + (part[2][t] + part[3][t]);  // atW
    if (t < 128) {
        float ap = (partp[0][t] + partp[1][t]) + (partp[2][t] + partp[3][t]);
        att_bf[b * 128 + t] = f2bf(ap);
    }
    if (w == 0) {
        float v0 = red_s[lane];
        float v1 = red_s[lane + 64];
        float v2 = (lane == 0) ? red_s[128] : -1e30f;
        float m = fmaxf(fmaxf(v0, v1), v2);
#pragma unroll
        for (int s = 1; s < 64; s <<= 1) m = fmaxf(m, __shfl_xor(m, s));
        float ssum = __expf(v0 - m) + __expf(v1 - m) + ((lane == 0) ? __expf(v2 - m) : 0.f);
#pragma unroll
        for (int s = 1; s < 64; s <<= 1) ssum += __shfl_xor(ssum, s);
        if (lane == 0) { mS[0] = m; mS[1] = logf(ssum); }
    }
    __syncthreads();
    if (t < RR) log_p_rule[b * RR + t] = red_s[t] - mS[0] - mS[1];

    float g0 = gl_s[0], g1 = gl_s[1];
    float gm = fmaxf(g0, g1);
    float e0g = __expf(g0 - gm), e1g = __expf(g1 - gm);
    float gate1 = e1g / (e0g + e1g);
    if (t == 0) gate0_ws[b] = e0g / (e0g + e1g);

    // ---- phase 7: pointer scores from LDS enc, lane-per-l ----
    {
        const int sl = ((w >> 1) << 6) + lane;
        float sp = 0.f;
        if (sl < LL) {
            const u32* __restrict__ rp = enc_u + sl * ROWU + ((w & 1) << 6);
            const float* __restrict__ ap = hc_s + DD + ((w & 1) << 7);
#pragma unroll 16
            for (int k = 0; k < 64; ++k) {
                u32 v = rp[k];
                sp = fmaf(bf2f((u16)v),         ap[2 * k],     sp);
                sp = fmaf(bf2f((u16)(v >> 16)), ap[2 * k + 1], sp);
            }
        }
        part[w][lane] = sp;
    }
    __syncthreads();
    if (t < LL) sc_s[t] = part[(t >> 6) << 1][t & 63] + part[((t >> 6) << 1) + 1][t & 63];
    __syncthreads();
    if (w == 0) {
        float v0 = sc_s[lane];
        float v1 = (lane + 64 < LL) ? sc_s[lane + 64] : -1e30f;
        float m = fmaxf(v0, v1);
#pragma unroll
        for (int s = 1; s < 64; s <<= 1) m = fmaxf(m, __shfl_xor(m, s));
        float ee0 = __expf(v0 - m);
        float ee1 = (lane + 64 < LL) ? __expf(v1 - m) : 0.f;
        float ssum = ee0 + ee1;
#pragma unroll
        for (int s = 1; s < 64; s <<= 1) ssum += __shfl_xor(ssum, s);
        float inv = 1.f / ssum;
        copy_mass[b * LL + lane] = gate1 * ee0 * inv;
        if (lane + 64 < LL) copy_mass[b * LL + lane + 64] = gate1 * ee1 * inv;
    }
}

// ---------------------------------------------------------------------------
// K7: logits = prim_bf (M) x att_bf (N) via bf16 MFMA, K=128, no max needed.
// ---------------------------------------------------------------------------
template <int PASS>
__global__ __launch_bounds__(256) void k_prim(
    const u16* __restrict__ att_bf, const u16* __restrict__ prim_bf,
    const float* __restrict__ coef, float* __restrict__ stats, float* __restrict__ p_prim)
{
    const int t = threadIdx.x;
    const int lane = t & 63, w = t >> 6;
    const int lm = lane & 15, lq = lane >> 4;
    const int colbase = blockIdx.x * 128 + (w & 1) * 64;
    const int chunk = colbase >> 6;
    const int rowblk = blockIdx.y * 256;

    s16x8 pfr[4][4];
#pragma unroll
    for (int kg = 0; kg < 4; ++kg)
#pragma unroll
        for (int mg = 0; mg < 4; ++mg)
            pfr[kg][mg] = *reinterpret_cast<const s16x8*>(
                &prim_bf[(size_t)(colbase + mg * 16 + lm) * 128 + kg * 32 + lq * 8]);

    for (int it = 0; it < 2; ++it) {
        const int rowbase = rowblk + it * 128 + (w >> 1) * 64;
        f32x4 acc[4][4] = {};
#pragma unroll
        for (int kg = 0; kg < 4; ++kg) {
            s16x8 afr[4];
#pragma unroll
            for (int ng = 0; ng < 4; ++ng)
                afr[ng] = *reinterpret_cast<const s16x8*>(
                    &att_bf[(rowbase + ng * 16 + lm) * 128 + kg * 32 + lq * 8]);
#pragma unroll
            for (int mg = 0; mg < 4; ++mg)
#pragma unroll
                for (int ng = 0; ng < 4; ++ng)
                    acc[mg][ng] = __builtin_amdgcn_mfma_f32_16x16x32_bf16(
                        pfr[kg][mg], afr[ng], acc[mg][ng], 0, 0, 0);
        }
        if (PASS == 0) {
#pragma unroll
            for (int ng = 0; ng < 4; ++ng) {
                float se = 0.f;
#pragma unroll
                for (int mg = 0; mg < 4; ++mg)
                    se += __expf(acc[mg][ng][0]) + __expf(acc[mg][ng][1])
                        + __expf(acc[mg][ng][2]) + __expf(acc[mg][ng][3]);
                se += __shfl_xor(se, 16);
                se += __shfl_xor(se, 32);
                if (lq == 0)
                    stats[chunk * NB + rowbase + ng * 16 + lm] = se;
            }
        } else {
#pragma unroll
            for (int ng = 0; ng < 4; ++ng) {
                const int arow = rowbase + ng * 16 + lm;
                const float cf = coef[arow];
                float* __restrict__ dst = &p_prim[(size_t)arow * VV + colbase + lq * 4];
#pragma unroll
                for (int mg = 0; mg < 4; ++mg) {
                    f32x4 v;
                    v[0] = cf * __expf(acc[mg][ng][0]);
                    v[1] = cf * __expf(acc[mg][ng][1]);
                    v[2] = cf * __expf(acc[mg][ng][2]);
                    v[3] = cf * __expf(acc[mg][ng][3]);
                    *reinterpret_cast<f32x4*>(&dst[mg * 16]) = v;
                }
            }
        }
    }
}

// ---------------------------------------------------------------------------
// K8: combine chunk-major sumexp -> coef = gate0/total (coalesced).
// ---------------------------------------------------------------------------
__global__ __launch_bounds__(256) void k_combine(
    const float* __restrict__ stats, const float* __restrict__ gate0_ws,
    float* __restrict__ coef)
{
    const int row = blockIdx.x * 256 + threadIdx.x;
    float s0 = 0.f, s1 = 0.f, s2 = 0.f, s3 = 0.f;
    for (int c = 0; c < 500; c += 4) {
        s0 += stats[(c)     * NB + row];
        s1 += stats[(c + 1) * NB + row];
        s2 += stats[(c + 2) * NB + row];
        s3 += stats[(c + 3) * NB + row];
    }
    coef[row] = gate0_ws[row] / ((s0 + s1) + (s2 + s3));
}

// ---------------------------------------------------------------------------
// K9: scatter copy mass into p_prim rows
// ---------------------------------------------------------------------------
__global__ __launch_bounds__(256) void k_scatter(
    const int* __restrict__ tok, const float* __restrict__ copy_mass, float* __restrict__ p_prim)
{
    int i = blockIdx.x * 256 + threadIdx.x;
    if (i >= NB * LL) return;
    int b = i / LL;
    atomicAdd(&p_prim[(size_t)b * VV + tok[i]], copy_mass[i]);
}

// ---------------------------------------------------------------------------
extern "C" void kernel_launch(void* const* d_in, const int* in_sizes, int n_in,
                              void* d_out, int out_size, void* d_ws, size_t ws_size,
                              hipStream_t stream)
{
    const float* x         = (const float*)d_in[0];
    const float* h0        = (const float*)d_in[1];
    const float* c0        = (const float*)d_in[2];
    const float* src_enc   = (const float*)d_in[3];
    const int*   tok       = (const int*)  d_in[4];
    const float* W_ih      = (const float*)d_in[5];
    const float* b_ih      = (const float*)d_in[6];
    const float* W_hh      = (const float*)d_in[7];
    const float* b_hh      = (const float*)d_in[8];
    const float* W_attn    = (const float*)d_in[9];
    const float* W_att_vec = (const float*)d_in[10];
    const float* W_ptr     = (const float*)d_in[11];
    const float* rule_emb  = (const float*)d_in[12];
    const float* W_rule_pr = (const float*)d_in[13];
    const float* prim_emb  = (const float*)d_in[14];
    const float* W_prim_pr = (const float*)d_in[15];
    const float* w_gen     = (const float*)d_in[16];
    const float* b_gen     = (const float*)d_in[17];

    float* out    = (float*)d_out;
    float* o_logp = out;                               // [1024,129]
    float* o_pp   = out + 1024 * 129;                  // [1024,32000]
    float* o_h    = o_pp + (size_t)1024 * 32000;       // [1024,256]
    float* o_c    = o_h + 1024 * 256;                  // [1024,256]
    float* o_att  = o_c + 1024 * 256;                  // [1024,256]

    float* wsf      = (float*)d_ws;
    float* ws_rp    = wsf;                     // 33280
    float* ws_gate  = ws_rp    + 33280;        // 1024
    float* ws_cm    = ws_gate  + 1024;         // 102400
    float* ws_coef  = ws_cm    + 102400;       // 1024
    float* ws_stats = ws_coef  + 1024;         // 512000 (500 chunks x 1024 rows)
    float* ws_wt    = ws_stats + 512000;       // 131072 (W_att_vec^T, 512x256)
    u16*   ws_attbf = (u16*)(ws_wt + 131072);            // 131072 u16
    u16*   ws_primbf= (u16*)(ws_wt + 131072 + 65536);    // 4096000 u16

    k_conv<<<dim3(2032), 256, 0, stream>>>(prim_emb, ws_primbf, rule_emb, W_rule_pr,
                                           ws_rp, W_att_vec, ws_wt);
    k_lstm<<<dim3(32, 16), 256, 0, stream>>>(x, h0, c0, W_ih, b_ih, W_hh, b_hh, o_h, o_c);
    k_fused<<<dim3(1024), 256, 0, stream>>>(src_enc, o_h, W_attn, ws_wt, ws_rp, W_ptr,
                                            W_prim_pr, w_gen, b_gen,
                                            o_att, o_logp, ws_attbf, ws_gate, ws_cm);
    k_prim<0><<<dim3(250, 4), 256, 0, stream>>>(ws_attbf, ws_primbf, nullptr, ws_stats, nullptr);
    k_combine<<<dim3(4), 256, 0, stream>>>(ws_stats, ws_gate, ws_coef);
    k_prim<1><<<dim3(250, 4), 256, 0, stream>>>(ws_attbf, ws_primbf, ws_coef, nullptr, o_pp);
    k_scatter<<<dim3(400), 256, 0, stream>>>(tok, ws_cm, o_pp);
}